// Round 8
// baseline (1154.222 us; speedup 1.0000x reference)
//
#include <hip/hip_runtime.h>
#include <hip/hip_bf16.h>
#include <math.h>

#define DEV __device__ __forceinline__

typedef short short8 __attribute__((ext_vector_type(8)));
typedef float f32x4  __attribute__((ext_vector_type(4)));

DEV float sigf(float x)   { return 1.0f / (1.0f + __expf(-x)); }
DEV float tanhft(float x) { return 1.0f - 2.0f / (__expf(2.0f * x) + 1.0f); }

// float -> bf16 (round to nearest even), as raw u16
DEV unsigned short f2bf(float f) {
    unsigned int u = __float_as_uint(f);
    unsigned int r = (u + 0x7FFFu + ((u >> 16) & 1u)) >> 16;
    return (unsigned short)r;
}
DEV float bf2f(unsigned short u) {
    return __uint_as_float(((unsigned int)u) << 16);
}

// LDS-only barrier: drain LDS ops but leave global loads (vmcnt) in flight.
DEV void bar_lds() {
    asm volatile("s_waitcnt lgkmcnt(0)" ::: "memory");
    __builtin_amdgcn_s_barrier();
}

// ---------------------------------------------------------------------------
// prep: recurrent weights -> bf16 (natural [col][128] layout), bias sums.
// ---------------------------------------------------------------------------
__global__ __launch_bounds__(256) void prep_kernel(
    const float* __restrict__ w_hh0, const float* __restrict__ w_ih1,
    const float* __restrict__ w_hh1,
    const float* __restrict__ b_ih0, const float* __restrict__ b_hh0,
    const float* __restrict__ b_ih1, const float* __restrict__ b_hh1,
    unsigned short* __restrict__ whh0h, unsigned short* __restrict__ wih1h,
    unsigned short* __restrict__ whh1h,
    float* __restrict__ bias0, float* __restrict__ bias1)
{
    int i = blockIdx.x * 256 + threadIdx.x;
    if (i < 65536) {
        whh0h[i] = f2bf(w_hh0[i]);
        wih1h[i] = f2bf(w_ih1[i]);
        whh1h[i] = f2bf(w_hh1[i]);
    } else if (i < 66048) {
        int c = i - 65536;
        bias0[c] = b_ih0[c] + b_hh0[c];
        bias1[c] = b_ih1[c] + b_hh1[c];
    }
}

// prep iw1 -> bf16 [256][2528], zero-padded K 2500..2527
__global__ __launch_bounds__(256) void prep_iw1_kernel(
    const float* __restrict__ iw1, unsigned short* __restrict__ iw1b)
{
    int i = blockIdx.x * 256 + threadIdx.x;
    if (i < 256 * 2528) {
        int row = i / 2528, k = i - row * 2528;
        iw1b[i] = (k < 2500) ? f2bf(iw1[row * 2500 + k]) : (unsigned short)0;
    }
}

// ---------------------------------------------------------------------------
// MFMA LSTM v6 = R4/R5-verified structure (ONE barrier/step, per-wave wsc,
// w_hh0/w_ih1 resident, w_hh1 streamed with split prefetch) at 2 ROWS/BLOCK
// for 2 blocks/CU occupancy: grid 512, __launch_bounds__(512,4) pins
// VGPR <= 128 (the 4-waves/SIMD boundary; kernel naturally sits at ~124).
// A co-resident INDEPENDENT block fills every barrier stall — no new
// hazards, no register-structure change (R3/R7 lesson). Rows 2..15 of the
// M=16 tile stay zero; update/output guarded q<2.
// LDS: xs 2432 + h0s/h1s 17408 + wsc 8192 + wih0s 10240 = 38272 B (x2/CU).
// ---------------------------------------------------------------------------
__global__ __launch_bounds__(512, 4) void lstm_kernel(
    const float* __restrict__ x,
    const unsigned short* __restrict__ whh0,
    const unsigned short* __restrict__ wih1,
    const unsigned short* __restrict__ whh1,
    const float* __restrict__ wih0,
    const float* __restrict__ bias0, const float* __restrict__ bias1,
    float* __restrict__ h2out)
{
    __shared__ __align__(16) float          xs[2][304];
    __shared__ __align__(16) unsigned short h0s[2][16][136];
    __shared__ __align__(16) unsigned short h1s[2][16][136];
    __shared__ __align__(16) float          wsc[8][4][16][4]; // [wave][g][col][row]
    __shared__ float wih0s[2560];

    const int tid = threadIdx.x;
    const int b0  = blockIdx.x * 2;
    const int l15 = tid & 15;          // MFMA A-row / C-col lane index
    const int q   = (tid >> 4) & 3;    // lane quad == owned batch row (q<2 valid)
    const int w   = tid >> 6;          // wave 0..7
    const int j   = w * 16 + l15;      // owned hidden unit 0..127
    const int q8  = q * 8;

    // ---- stage x (2 rows), w_ih0; zero h buffers (rows 2..15 stay zero)
    for (int i = tid; i < 600; i += 512) {
        int m = i / 300, kk = i - m * 300;
        xs[m][kk] = x[(b0 + m) * 300 + kk];
    }
    for (int i = tid; i < 2560; i += 512) wih0s[i] = wih0[i];
    for (int i = tid; i < 2176; i += 512) {
        ((unsigned int*)h0s)[i] = 0u;
        ((unsigned int*)h1s)[i] = 0u;
    }

    // ---- per-lane biases for unit j (loop-invariant, 8 regs)
    float ub0[4], ub1[4];
#pragma unroll
    for (int g = 0; g < 4; ++g) {
        ub0[g] = bias0[g * 128 + j];
        ub1[g] = bias1[g * 128 + j];
    }

    // ---- resident B-fragments: w_hh0, w_ih1 (w_hh1 is streamed)
    short8 bh0[4][4], b1i[4][4];
#pragma unroll
    for (int g = 0; g < 4; ++g)
#pragma unroll
        for (int kc = 0; kc < 4; ++kc) {
            int off = (g * 128 + j) * 128 + kc * 32 + q8;
            bh0[g][kc] = *(const short8*)(whh0 + off);
            b1i[g][kc] = *(const short8*)(wih1 + off);
        }

    float c0 = 0.f, c1 = 0.f, hl = 0.f;
    __syncthreads();

    const unsigned short* wsb = whh1 + j * 128 + q8;  // per-lane stream base

    for (int t = 0; t < 60; ++t) {
        const int p = t & 1;

        // ---- prefetch streamed w_hh1, first half (in flight across BAR)
        short8 wsv[4][4];
#pragma unroll
        for (int g = 0; g < 4; ++g) {
            wsv[g][0] = *(const short8*)(wsb + g * 16384);
            wsv[g][1] = *(const short8*)(wsb + g * 16384 + 32);
        }

        // ================= phase A: layer 0 =================
        f32x4 acc[4];
#pragma unroll
        for (int g = 0; g < 4; ++g) acc[g] = (f32x4){0.f, 0.f, 0.f, 0.f};
        short8 af[4];
#pragma unroll
        for (int kc = 0; kc < 4; ++kc)
            af[kc] = *(const short8*)&h0s[p][l15][kc * 32 + q8];
#pragma unroll
        for (int kc = 0; kc < 4; ++kc)
#pragma unroll
            for (int g = 0; g < 4; ++g)
                acc[g] = __builtin_amdgcn_mfma_f32_16x16x32_bf16(af[kc], bh0[g][kc], acc[g], 0, 0, 0);

        // ---- prefetch streamed w_hh1, second half
#pragma unroll
        for (int g = 0; g < 4; ++g) {
            wsv[g][2] = *(const short8*)(wsb + g * 16384 + 64);
            wsv[g][3] = *(const short8*)(wsb + g * 16384 + 96);
        }

        // intra-wave redistribute: q==0 lanes publish rows 0..3 of 16 cols
        if (q == 0) {
#pragma unroll
            for (int g = 0; g < 4; ++g)
                *(f32x4*)&wsc[w][g][l15][0] = acc[g];
        }
        // each valid lane picks up (row=q, unit=j); lgkmcnt orders intra-wave
        if (q < 2) {
            const float* xr = &xs[q][t * 5];
            float x0 = xr[0], x1 = xr[1], x2 = xr[2], x3 = xr[3], x4 = xr[4];
            float gv[4];
#pragma unroll
            for (int g = 0; g < 4; ++g) {
                const float* wr = &wih0s[(g * 128 + j) * 5];
                float s = wsc[w][g][l15][q] + ub0[g];
                s = fmaf(x0, wr[0], s);
                s = fmaf(x1, wr[1], s);
                s = fmaf(x2, wr[2], s);
                s = fmaf(x3, wr[3], s);
                gv[g] = fmaf(x4, wr[4], s);
            }
            c0 = sigf(gv[1]) * c0 + sigf(gv[0]) * tanhft(gv[2]);
            float h = sigf(gv[3]) * tanhft(c0);
            h0s[1 - p][q][j] = f2bf(h);
        }

        bar_lds();  // the ONLY barrier per step

        // ================= phase B: layer 1 =================
#pragma unroll
        for (int g = 0; g < 4; ++g) acc[g] = (f32x4){0.f, 0.f, 0.f, 0.f};
#pragma unroll
        for (int kc = 0; kc < 4; ++kc)
            af[kc] = *(const short8*)&h0s[1 - p][l15][kc * 32 + q8];
#pragma unroll
        for (int kc = 0; kc < 4; ++kc)
#pragma unroll
            for (int g = 0; g < 4; ++g)
                acc[g] = __builtin_amdgcn_mfma_f32_16x16x32_bf16(af[kc], b1i[g][kc], acc[g], 0, 0, 0);
#pragma unroll
        for (int kc = 0; kc < 4; ++kc)
            af[kc] = *(const short8*)&h1s[p][l15][kc * 32 + q8];
#pragma unroll
        for (int kc = 0; kc < 4; ++kc)
#pragma unroll
            for (int g = 0; g < 4; ++g)
                acc[g] = __builtin_amdgcn_mfma_f32_16x16x32_bf16(af[kc], wsv[g][kc], acc[g], 0, 0, 0);

        if (q == 0) {
#pragma unroll
            for (int g = 0; g < 4; ++g)
                *(f32x4*)&wsc[w][g][l15][0] = acc[g];
        }
        if (q < 2) {
            float gv[4];
#pragma unroll
            for (int g = 0; g < 4; ++g)
                gv[g] = wsc[w][g][l15][q] + ub1[g];
            c1 = sigf(gv[1]) * c1 + sigf(gv[0]) * tanhft(gv[2]);
            float h = sigf(gv[3]) * tanhft(c1);
            h1s[1 - p][q][j] = f2bf(h);
            hl = h;
        }
        // no barrier: next step's bar_lds covers h1/h0/wsc hazards
    }

    if (q < 2) h2out[(b0 + q) * 128 + j] = hl;
}

// ---------------------------------------------------------------------------
// phase2 v2 (R5-verified): base = tanh(relu(h2 @ pw1^T + pb1) @ pw2^T + pb2).
// ---------------------------------------------------------------------------
__global__ __launch_bounds__(256) void phase2_kernel(
    const float* __restrict__ h2, const float* __restrict__ pw1,
    const float* __restrict__ pb1, const float* __restrict__ pw2,
    const float* __restrict__ pb2, float* __restrict__ base)
{
    __shared__ float pw1s[64 * 129];
    __shared__ float pw2s[32 * 65];
    __shared__ float hs[4][128];
    __shared__ float p1s[4][64];

    const int tid = threadIdx.x;
    const int b0  = blockIdx.x * 4;

    for (int i = tid; i < 8192; i += 256) {
        int u = i >> 7, k = i & 127;
        pw1s[u * 129 + k] = pw1[i];
    }
    for (int i = tid; i < 2048; i += 256) {
        int u = i >> 6, k = i & 63;
        pw2s[u * 65 + k] = pw2[i];
    }
    for (int i = tid; i < 512; i += 256)
        hs[i >> 7][i & 127] = h2[b0 * 128 + i];
    __syncthreads();

    {
        const int r = tid >> 6, u = tid & 63;
        float acc = pb1[u];
        const float* wr = &pw1s[u * 129];
        const float* hr = &hs[r][0];
#pragma unroll 4
        for (int k = 0; k < 128; ++k) acc = fmaf(hr[k], wr[k], acc);
        p1s[r][u] = fmaxf(acc, 0.f);
    }
    __syncthreads();

    if (tid < 128) {
        const int r = tid >> 5, u2 = tid & 31;
        float a2 = pb2[u2];
        const float* wr = &pw2s[u2 * 65];
        const float* pr = &p1s[r][0];
#pragma unroll 4
        for (int k = 0; k < 64; ++k) a2 = fmaf(pr[k], wr[k], a2);
        base[(b0 + r) * 32 + u2] = tanhft(a2);
    }
}

// ---------------------------------------------------------------------------
// W_eff^T[j][n] = sum_{k: conn_idx[n,k]%32==j} conn_w[n,k]
// ---------------------------------------------------------------------------
__global__ __launch_bounds__(128) void weff_kernel(
    const int* __restrict__ conn_idx, const float* __restrict__ conn_w,
    float* __restrict__ weffT)
{
    __shared__ float s[128 * 33];
    int tid = threadIdx.x;
    int n = blockIdx.x * 128 + tid;
    float* sr = &s[tid * 33];
#pragma unroll
    for (int j = 0; j < 32; ++j) sr[j] = 0.f;
    if (n < 2500) {
        for (int k = 0; k < 50; ++k) {
            int idx = conn_idx[n * 50 + k];
            sr[idx & 31] += conn_w[n * 50 + k];
        }
        for (int j = 0; j < 32; ++j) weffT[j * 2500 + n] = sr[j];
    }
}

// ---------------------------------------------------------------------------
// z = (base @ W_eff^T)*sens; a = per-group activation. amat stored bf16
// [b][2528] (K-padded with zeros for the MFMA GEMM).
// ---------------------------------------------------------------------------
__global__ __launch_bounds__(256) void za_kernel(
    const float* __restrict__ base, const float* __restrict__ weffT,
    const float* __restrict__ sens, const float* __restrict__ thr,
    unsigned short* __restrict__ amat)
{
    __shared__ float bs[16][32];
    int tid = threadIdx.x;
    int bb = blockIdx.x / 10, nb = blockIdx.x % 10;
    int n = nb * 256 + tid;
    bool nv = n < 2500;
    bool pv = n < 2528;
    int nn = nv ? n : 0;
    for (int i = tid; i < 512; i += 256) bs[i >> 5][i & 31] = base[bb * 512 + i];
    __syncthreads();
    float w[32];
#pragma unroll
    for (int j = 0; j < 32; ++j) w[j] = weffT[j * 2500 + nn];
    float sn = sens[nn], tn = thr[nn];
    int g = (n < 800) ? 0 : (n < 1500) ? 1 : (n < 2100) ? 2 : 3;
#pragma unroll 2
    for (int r = 0; r < 16; ++r) {
        float z = 0.f;
#pragma unroll
        for (int j = 0; j < 32; ++j) z = fmaf(bs[r][j], w[j], z);
        z *= sn;
        float av;
        if (g == 0)      av = sigf(z - tn);
        else if (g == 1) av = tanhft(z);
        else if (g == 2) av = fmaxf(z - tn, 0.f);
        else             av = sigf(z);
        if (nv)      amat[(bb * 16 + r) * 2528 + n] = f2bf(av);
        else if (pv) amat[(bb * 16 + r) * 2528 + n] = 0;
    }
}

// ---------------------------------------------------------------------------
// t1 = relu(a @ iw1^T + ib1): M=1024 N=256 K=2528(padded), bf16 MFMA.
// R5-verified: grid (8,32) = 256 blocks x 128 thr, 1-deep prefetch.
// ---------------------------------------------------------------------------
__global__ __launch_bounds__(128) void gemm_iw1_kernel(
    const unsigned short* __restrict__ ab, const unsigned short* __restrict__ wb,
    const float* __restrict__ ib1, float* __restrict__ t1)
{
    const int tid = threadIdx.x;
    const int wv  = tid >> 6;
    const int l15 = tid & 15, q = (tid >> 4) & 3, q8 = q * 8;
    const int row0 = blockIdx.y * 32 + wv * 16;
    const int col0 = blockIdx.x * 32;

    const unsigned short* A = ab + (row0 + l15) * 2528 + q8;
    const unsigned short* B = wb + (col0 + l15) * 2528 + q8;

    short8 a = *(const short8*)A;
    short8 b[2];
#pragma unroll
    for (int nt = 0; nt < 2; ++nt) b[nt] = *(const short8*)(B + nt * 16 * 2528);

    f32x4 acc[2];
#pragma unroll
    for (int nt = 0; nt < 2; ++nt) acc[nt] = (f32x4){0.f, 0.f, 0.f, 0.f};

    for (int c = 0; c < 79; ++c) {
        int cn = (c < 78) ? c + 1 : 78;
        short8 an = *(const short8*)(A + cn * 32);
        short8 bn[2];
#pragma unroll
        for (int nt = 0; nt < 2; ++nt)
            bn[nt] = *(const short8*)(B + nt * 16 * 2528 + cn * 32);
#pragma unroll
        for (int nt = 0; nt < 2; ++nt)
            acc[nt] = __builtin_amdgcn_mfma_f32_16x16x32_bf16(a, b[nt], acc[nt], 0, 0, 0);
        a = an;
#pragma unroll
        for (int nt = 0; nt < 2; ++nt) b[nt] = bn[nt];
    }

#pragma unroll
    for (int nt = 0; nt < 2; ++nt) {
        int n = col0 + nt * 16 + l15;
        float bias = ib1[n];
#pragma unroll
        for (int i = 0; i < 4; ++i) {
            int row = row0 + q * 4 + i;
            t1[row * 256 + n] = fmaxf(acc[nt][i] + bias, 0.f);
        }
    }
}

// ---------------------------------------------------------------------------
// final v2 (R5-verified): t2 = relu(t1@iw2^T+ib2); integ = tanh(t2@iw3^T+ib3);
// heads. 256 blocks x 256 thr, iw2/iw3 LDS-staged (257/65 padding).
// ---------------------------------------------------------------------------
__global__ __launch_bounds__(256) void final_kernel(
    const float* __restrict__ t1, const float* __restrict__ iw2,
    const float* __restrict__ ib2, const float* __restrict__ iw3,
    const float* __restrict__ ib3,
    const float* __restrict__ hw_trend, const float* __restrict__ hb_trend,
    const float* __restrict__ hw_pat,   const float* __restrict__ hb_pat,
    const float* __restrict__ hw_key,   const float* __restrict__ hb_key,
    const float* __restrict__ hw_vol,   const float* __restrict__ hb_vol,
    const float* __restrict__ hw_conf,  const float* __restrict__ hb_conf,
    float* __restrict__ out)
{
    __shared__ float iw2s[64 * 257];
    __shared__ float iw3s[32 * 65];
    __shared__ float t1s[4][256];
    __shared__ float t2s[4][64];
    __shared__ float igs[4][32];

    const int tid = threadIdx.x;
    const int b0  = blockIdx.x * 4;

    for (int i = tid; i < 16384; i += 256) {
        int u = i >> 8, k = i & 255;
        iw2s[u * 257 + k] = iw2[i];
    }
    for (int i = tid; i < 2048; i += 256) {
        int u = i >> 6, k = i & 63;
        iw3s[u * 65 + k] = iw3[i];
    }
    for (int i = tid; i < 1024; i += 256)
        t1s[i >> 8][i & 255] = t1[b0 * 256 + i];
    __syncthreads();

    {
        const int r = tid >> 6, u = tid & 63;
        float acc = ib2[u];
        const float* wr = &iw2s[u * 257];
        const float* tr = &t1s[r][0];
#pragma unroll 4
        for (int k = 0; k < 256; ++k) acc = fmaf(tr[k], wr[k], acc);
        t2s[r][u] = fmaxf(acc, 0.f);
    }
    __syncthreads();

    if (tid < 128) {
        const int r = tid >> 5, u2 = tid & 31;
        float a2 = ib3[u2];
        const float* wr = &iw3s[u2 * 65];
        const float* tr = &t2s[r][0];
#pragma unroll 4
        for (int k = 0; k < 64; ++k) a2 = fmaf(tr[k], wr[k], a2);
        igs[r][u2] = tanhft(a2);
    }
    __syncthreads();

    if (tid < 60) {
        const int r = tid / 15, t15 = tid % 15;
        const int b = b0 + r;
        const float* w; const float* bb; int j, off;
        if (t15 < 3)        { w = hw_trend; bb = hb_trend; j = t15;     off = 0; }
        else if (t15 < 9)   { w = hw_pat;   bb = hb_pat;   j = t15 - 3; off = 3; }
        else if (t15 < 13)  { w = hw_key;   bb = hb_key;   j = t15 - 9; off = 9; }
        else if (t15 == 13) { w = hw_vol;   bb = hb_vol;   j = 0;       off = 13; }
        else                { w = hw_conf;  bb = hb_conf;  j = 0;       off = 14; }
        float a3 = bb[j];
#pragma unroll
        for (int k = 0; k < 32; ++k) a3 = fmaf(igs[r][k], w[j * 32 + k], a3);
        out[b * 20 + off + j] = a3;
        if (t15 == 14) out[b * 20 + 15] = sigf(a3);
    }
}

// ---------------------------------------------------------------------------
// group means of a (bf16, padded pitch 2528) -> out[:, 16:20]
// ---------------------------------------------------------------------------
__global__ __launch_bounds__(256) void means_kernel(
    const unsigned short* __restrict__ amat, float* __restrict__ out)
{
    __shared__ float red[16];
    int b = blockIdx.x, tid = threadIdx.x;
    float parts[4] = {0.f, 0.f, 0.f, 0.f};
    for (int n0 = tid * 8; n0 < 2500; n0 += 2048) {
        short8 v = *(const short8*)(amat + b * 2528 + n0);
#pragma unroll
        for (int e = 0; e < 8; ++e) {
            int n = n0 + e;
            float f = bf2f((unsigned short)v[e]);
            if (n < 800)       parts[0] += f;
            else if (n < 1500) parts[1] += f;
            else if (n < 2100) parts[2] += f;
            else               parts[3] += f;   // n in [2500,2528) pad adds 0
        }
    }
    int lane = tid & 63, wv = tid >> 6;
#pragma unroll
    for (int g = 0; g < 4; ++g) {
        float v = parts[g];
        for (int s = 32; s > 0; s >>= 1) v += __shfl_down(v, s, 64);
        if (lane == 0) red[wv * 4 + g] = v;
    }
    __syncthreads();
    if (tid < 4) {
        float s = red[tid] + red[4 + tid] + red[8 + tid] + red[12 + tid];
        float invg = (tid == 0) ? (1.f / 800.f) : (tid == 1) ? (1.f / 700.f)
                   : (tid == 2) ? (1.f / 600.f) : (1.f / 400.f);
        out[b * 20 + 16 + tid] = s * invg;
    }
}

// ---------------------------------------------------------------------------
extern "C" void kernel_launch(void* const* d_in, const int* in_sizes, int n_in,
                              void* d_out, int out_size, void* d_ws, size_t ws_size,
                              hipStream_t stream)
{
    const float* x        = (const float*)d_in[0];
    const int*   conn_idx = (const int*)  d_in[1];
    const float* w_ih0    = (const float*)d_in[2];
    const float* w_hh0    = (const float*)d_in[3];
    const float* b_ih0    = (const float*)d_in[4];
    const float* b_hh0    = (const float*)d_in[5];
    const float* w_ih1    = (const float*)d_in[6];
    const float* w_hh1    = (const float*)d_in[7];
    const float* b_ih1    = (const float*)d_in[8];
    const float* b_hh1    = (const float*)d_in[9];
    const float* pw1      = (const float*)d_in[10];
    const float* pb1      = (const float*)d_in[11];
    const float* pw2      = (const float*)d_in[12];
    const float* pb2      = (const float*)d_in[13];
    const float* conn_w   = (const float*)d_in[14];
    const float* sens     = (const float*)d_in[15];
    const float* thr      = (const float*)d_in[16];
    const float* iw1      = (const float*)d_in[17];
    const float* ib1      = (const float*)d_in[18];
    const float* iw2      = (const float*)d_in[19];
    const float* ib2      = (const float*)d_in[20];
    const float* iw3      = (const float*)d_in[21];
    const float* ib3      = (const float*)d_in[22];
    const float* hw_trend = (const float*)d_in[23];
    const float* hb_trend = (const float*)d_in[24];
    const float* hw_pat   = (const float*)d_in[25];
    const float* hb_pat   = (const float*)d_in[26];
    const float* hw_key   = (const float*)d_in[27];
    const float* hb_key   = (const float*)d_in[28];
    const float* hw_vol   = (const float*)d_in[29];
    const float* hb_vol   = (const float*)d_in[30];
    const float* hw_conf  = (const float*)d_in[31];
    const float* hb_conf  = (const float*)d_in[32];
    float* out = (float*)d_out;
    float* ws  = (float*)d_ws;

    // ws layout (float slots)
    unsigned short* whh0h = (unsigned short*)(ws);           // 32768 f
    unsigned short* wih1h = (unsigned short*)(ws + 32768);   // 32768 f
    unsigned short* whh1h = (unsigned short*)(ws + 65536);   // 32768 f
    float* bias0  = ws + 98304;   // 512
    float* bias1  = ws + 98816;   // 512
    float* h2     = ws + 99328;   // 131072
    float* base_  = ws + 230400;  // 32768
    float* weffT  = ws + 263168;  // 80000
    float* t1     = ws + 343168;  // 262144
    unsigned short* iw1b   = (unsigned short*)(ws + 605312); // 323584 f
    unsigned short* amatbf = (unsigned short*)(ws + 928896); // 1294336 f -> ends 2223232

    prep_kernel<<<258, 256, 0, stream>>>(w_hh0, w_ih1, w_hh1,
                                         b_ih0, b_hh0, b_ih1, b_hh1,
                                         whh0h, wih1h, whh1h, bias0, bias1);
    prep_iw1_kernel<<<2528, 256, 0, stream>>>(iw1, iw1b);
    lstm_kernel<<<512, 512, 0, stream>>>(x, whh0h, wih1h, whh1h, w_ih0,
                                         bias0, bias1, h2);
    phase2_kernel<<<256, 256, 0, stream>>>(h2, pw1, pb1, pw2, pb2, base_);
    weff_kernel<<<20, 128, 0, stream>>>(conn_idx, conn_w, weffT);
    za_kernel<<<640, 256, 0, stream>>>(base_, weffT, sens, thr, amatbf);
    gemm_iw1_kernel<<<dim3(8, 32), 128, 0, stream>>>(amatbf, iw1b, ib1, t1);
    final_kernel<<<256, 256, 0, stream>>>(t1, iw2, ib2, iw3, ib3,
                                          hw_trend, hb_trend, hw_pat, hb_pat,
                                          hw_key, hb_key, hw_vol, hb_vol,
                                          hw_conf, hb_conf, out);
    means_kernel<<<1024, 256, 0, stream>>>(amatbf, out);
}

// Round 9
// 404.422 us; speedup vs baseline: 2.8540x; 2.8540x over previous
//
#include <hip/hip_runtime.h>
#include <hip/hip_bf16.h>
#include <math.h>

#define DEV __device__ __forceinline__

typedef short short8 __attribute__((ext_vector_type(8)));
typedef float f32x4  __attribute__((ext_vector_type(4)));

DEV float sigf(float x)   { return 1.0f / (1.0f + __expf(-x)); }
DEV float tanhft(float x) { return 1.0f - 2.0f / (__expf(2.0f * x) + 1.0f); }

// float -> bf16 (round to nearest even), as raw u16
DEV unsigned short f2bf(float f) {
    unsigned int u = __float_as_uint(f);
    unsigned int r = (u + 0x7FFFu + ((u >> 16) & 1u)) >> 16;
    return (unsigned short)r;
}
DEV float bf2f(unsigned short u) {
    return __uint_as_float(((unsigned int)u) << 16);
}

// LDS-only barrier: drain LDS ops but leave global loads (vmcnt) in flight.
DEV void bar_lds() {
    asm volatile("s_waitcnt lgkmcnt(0)" ::: "memory");
    __builtin_amdgcn_s_barrier();
}

// ---------------------------------------------------------------------------
// prep: recurrent weights -> bf16 (natural [col][128] layout), bias sums.
// ---------------------------------------------------------------------------
__global__ __launch_bounds__(256) void prep_kernel(
    const float* __restrict__ w_hh0, const float* __restrict__ w_ih1,
    const float* __restrict__ w_hh1,
    const float* __restrict__ b_ih0, const float* __restrict__ b_hh0,
    const float* __restrict__ b_ih1, const float* __restrict__ b_hh1,
    unsigned short* __restrict__ whh0h, unsigned short* __restrict__ wih1h,
    unsigned short* __restrict__ whh1h,
    float* __restrict__ bias0, float* __restrict__ bias1)
{
    int i = blockIdx.x * 256 + threadIdx.x;
    if (i < 65536) {
        whh0h[i] = f2bf(w_hh0[i]);
        wih1h[i] = f2bf(w_ih1[i]);
        whh1h[i] = f2bf(w_hh1[i]);
    } else if (i < 66048) {
        int c = i - 65536;
        bias0[c] = b_ih0[c] + b_hh0[c];
        bias1[c] = b_ih1[c] + b_hh1[c];
    }
}

// prep iw1 -> bf16 [256][2528], zero-padded K 2500..2527
__global__ __launch_bounds__(256) void prep_iw1_kernel(
    const float* __restrict__ iw1, unsigned short* __restrict__ iw1b)
{
    int i = blockIdx.x * 256 + threadIdx.x;
    if (i < 256 * 2528) {
        int row = i / 2528, k = i - row * 2528;
        iw1b[i] = (k < 2500) ? f2bf(iw1[row * 2500 + k]) : (unsigned short)0;
    }
}

// ---------------------------------------------------------------------------
// MFMA LSTM v7 = R4/R5-verified structure (ONE barrier/step, per-wave wsc,
// w_hh0/w_ih1 resident, w_hh1 streamed with split prefetch) at 2 ROWS/BLOCK,
// grid 512 => 2 blocks/CU co-residency to fill barrier stalls.
// __launch_bounds__(512, 2): the R0-R5-proven bound whose register budget
// (128 cap) this structure compiles into at VGPR~124. R8's (512,4) forced a
// 64-VGPR budget -> catastrophic spill (VGPR_Count 64, FETCH 3.35 GB); the
// second arg empirically scales the per-wave cap as 512/(2*arg).
// Rows 2..15 of the M=16 tile stay zero; update/output guarded q<2.
// LDS: xs 2432 + h0s/h1s 17408 + wsc 8192 + wih0s 10240 = 38272 B (x2/CU
// = 76.5 KB <= 160 KB).
// ---------------------------------------------------------------------------
__global__ __launch_bounds__(512, 2) void lstm_kernel(
    const float* __restrict__ x,
    const unsigned short* __restrict__ whh0,
    const unsigned short* __restrict__ wih1,
    const unsigned short* __restrict__ whh1,
    const float* __restrict__ wih0,
    const float* __restrict__ bias0, const float* __restrict__ bias1,
    float* __restrict__ h2out)
{
    __shared__ __align__(16) float          xs[2][304];
    __shared__ __align__(16) unsigned short h0s[2][16][136];
    __shared__ __align__(16) unsigned short h1s[2][16][136];
    __shared__ __align__(16) float          wsc[8][4][16][4]; // [wave][g][col][row]
    __shared__ float wih0s[2560];

    const int tid = threadIdx.x;
    const int b0  = blockIdx.x * 2;
    const int l15 = tid & 15;          // MFMA A-row / C-col lane index
    const int q   = (tid >> 4) & 3;    // lane quad == owned batch row (q<2 valid)
    const int w   = tid >> 6;          // wave 0..7
    const int j   = w * 16 + l15;      // owned hidden unit 0..127
    const int q8  = q * 8;

    // ---- stage x (2 rows), w_ih0; zero h buffers (rows 2..15 stay zero)
    for (int i = tid; i < 600; i += 512) {
        int m = i / 300, kk = i - m * 300;
        xs[m][kk] = x[(b0 + m) * 300 + kk];
    }
    for (int i = tid; i < 2560; i += 512) wih0s[i] = wih0[i];
    for (int i = tid; i < 2176; i += 512) {
        ((unsigned int*)h0s)[i] = 0u;
        ((unsigned int*)h1s)[i] = 0u;
    }

    // ---- per-lane biases for unit j (loop-invariant, 8 regs)
    float ub0[4], ub1[4];
#pragma unroll
    for (int g = 0; g < 4; ++g) {
        ub0[g] = bias0[g * 128 + j];
        ub1[g] = bias1[g * 128 + j];
    }

    // ---- resident B-fragments: w_hh0, w_ih1 (w_hh1 is streamed)
    short8 bh0[4][4], b1i[4][4];
#pragma unroll
    for (int g = 0; g < 4; ++g)
#pragma unroll
        for (int kc = 0; kc < 4; ++kc) {
            int off = (g * 128 + j) * 128 + kc * 32 + q8;
            bh0[g][kc] = *(const short8*)(whh0 + off);
            b1i[g][kc] = *(const short8*)(wih1 + off);
        }

    float c0 = 0.f, c1 = 0.f, hl = 0.f;
    __syncthreads();

    const unsigned short* wsb = whh1 + j * 128 + q8;  // per-lane stream base

    for (int t = 0; t < 60; ++t) {
        const int p = t & 1;

        // ---- prefetch streamed w_hh1, first half (in flight across BAR)
        short8 wsv[4][4];
#pragma unroll
        for (int g = 0; g < 4; ++g) {
            wsv[g][0] = *(const short8*)(wsb + g * 16384);
            wsv[g][1] = *(const short8*)(wsb + g * 16384 + 32);
        }

        // ================= phase A: layer 0 =================
        f32x4 acc[4];
#pragma unroll
        for (int g = 0; g < 4; ++g) acc[g] = (f32x4){0.f, 0.f, 0.f, 0.f};
        short8 af[4];
#pragma unroll
        for (int kc = 0; kc < 4; ++kc)
            af[kc] = *(const short8*)&h0s[p][l15][kc * 32 + q8];
#pragma unroll
        for (int kc = 0; kc < 4; ++kc)
#pragma unroll
            for (int g = 0; g < 4; ++g)
                acc[g] = __builtin_amdgcn_mfma_f32_16x16x32_bf16(af[kc], bh0[g][kc], acc[g], 0, 0, 0);

        // ---- prefetch streamed w_hh1, second half
#pragma unroll
        for (int g = 0; g < 4; ++g) {
            wsv[g][2] = *(const short8*)(wsb + g * 16384 + 64);
            wsv[g][3] = *(const short8*)(wsb + g * 16384 + 96);
        }

        // intra-wave redistribute: q==0 lanes publish rows 0..3 of 16 cols
        if (q == 0) {
#pragma unroll
            for (int g = 0; g < 4; ++g)
                *(f32x4*)&wsc[w][g][l15][0] = acc[g];
        }
        // each valid lane picks up (row=q, unit=j); lgkmcnt orders intra-wave
        if (q < 2) {
            const float* xr = &xs[q][t * 5];
            float x0 = xr[0], x1 = xr[1], x2 = xr[2], x3 = xr[3], x4 = xr[4];
            float gv[4];
#pragma unroll
            for (int g = 0; g < 4; ++g) {
                const float* wr = &wih0s[(g * 128 + j) * 5];
                float s = wsc[w][g][l15][q] + ub0[g];
                s = fmaf(x0, wr[0], s);
                s = fmaf(x1, wr[1], s);
                s = fmaf(x2, wr[2], s);
                s = fmaf(x3, wr[3], s);
                gv[g] = fmaf(x4, wr[4], s);
            }
            c0 = sigf(gv[1]) * c0 + sigf(gv[0]) * tanhft(gv[2]);
            float h = sigf(gv[3]) * tanhft(c0);
            h0s[1 - p][q][j] = f2bf(h);
        }

        bar_lds();  // the ONLY barrier per step

        // ================= phase B: layer 1 =================
#pragma unroll
        for (int g = 0; g < 4; ++g) acc[g] = (f32x4){0.f, 0.f, 0.f, 0.f};
#pragma unroll
        for (int kc = 0; kc < 4; ++kc)
            af[kc] = *(const short8*)&h0s[1 - p][l15][kc * 32 + q8];
#pragma unroll
        for (int kc = 0; kc < 4; ++kc)
#pragma unroll
            for (int g = 0; g < 4; ++g)
                acc[g] = __builtin_amdgcn_mfma_f32_16x16x32_bf16(af[kc], b1i[g][kc], acc[g], 0, 0, 0);
#pragma unroll
        for (int kc = 0; kc < 4; ++kc)
            af[kc] = *(const short8*)&h1s[p][l15][kc * 32 + q8];
#pragma unroll
        for (int kc = 0; kc < 4; ++kc)
#pragma unroll
            for (int g = 0; g < 4; ++g)
                acc[g] = __builtin_amdgcn_mfma_f32_16x16x32_bf16(af[kc], wsv[g][kc], acc[g], 0, 0, 0);

        if (q == 0) {
#pragma unroll
            for (int g = 0; g < 4; ++g)
                *(f32x4*)&wsc[w][g][l15][0] = acc[g];
        }
        if (q < 2) {
            float gv[4];
#pragma unroll
            for (int g = 0; g < 4; ++g)
                gv[g] = wsc[w][g][l15][q] + ub1[g];
            c1 = sigf(gv[1]) * c1 + sigf(gv[0]) * tanhft(gv[2]);
            float h = sigf(gv[3]) * tanhft(c1);
            h1s[1 - p][q][j] = f2bf(h);
            hl = h;
        }
        // no barrier: next step's bar_lds covers h1/h0/wsc hazards
    }

    if (q < 2) h2out[(b0 + q) * 128 + j] = hl;
}

// ---------------------------------------------------------------------------
// phase2 v2 (R5-verified): base = tanh(relu(h2 @ pw1^T + pb1) @ pw2^T + pb2).
// ---------------------------------------------------------------------------
__global__ __launch_bounds__(256) void phase2_kernel(
    const float* __restrict__ h2, const float* __restrict__ pw1,
    const float* __restrict__ pb1, const float* __restrict__ pw2,
    const float* __restrict__ pb2, float* __restrict__ base)
{
    __shared__ float pw1s[64 * 129];
    __shared__ float pw2s[32 * 65];
    __shared__ float hs[4][128];
    __shared__ float p1s[4][64];

    const int tid = threadIdx.x;
    const int b0  = blockIdx.x * 4;

    for (int i = tid; i < 8192; i += 256) {
        int u = i >> 7, k = i & 127;
        pw1s[u * 129 + k] = pw1[i];
    }
    for (int i = tid; i < 2048; i += 256) {
        int u = i >> 6, k = i & 63;
        pw2s[u * 65 + k] = pw2[i];
    }
    for (int i = tid; i < 512; i += 256)
        hs[i >> 7][i & 127] = h2[b0 * 128 + i];
    __syncthreads();

    {
        const int r = tid >> 6, u = tid & 63;
        float acc = pb1[u];
        const float* wr = &pw1s[u * 129];
        const float* hr = &hs[r][0];
#pragma unroll 4
        for (int k = 0; k < 128; ++k) acc = fmaf(hr[k], wr[k], acc);
        p1s[r][u] = fmaxf(acc, 0.f);
    }
    __syncthreads();

    if (tid < 128) {
        const int r = tid >> 5, u2 = tid & 31;
        float a2 = pb2[u2];
        const float* wr = &pw2s[u2 * 65];
        const float* pr = &p1s[r][0];
#pragma unroll 4
        for (int k = 0; k < 64; ++k) a2 = fmaf(pr[k], wr[k], a2);
        base[(b0 + r) * 32 + u2] = tanhft(a2);
    }
}

// ---------------------------------------------------------------------------
// W_eff^T[j][n] = sum_{k: conn_idx[n,k]%32==j} conn_w[n,k]
// ---------------------------------------------------------------------------
__global__ __launch_bounds__(128) void weff_kernel(
    const int* __restrict__ conn_idx, const float* __restrict__ conn_w,
    float* __restrict__ weffT)
{
    __shared__ float s[128 * 33];
    int tid = threadIdx.x;
    int n = blockIdx.x * 128 + tid;
    float* sr = &s[tid * 33];
#pragma unroll
    for (int j = 0; j < 32; ++j) sr[j] = 0.f;
    if (n < 2500) {
        for (int k = 0; k < 50; ++k) {
            int idx = conn_idx[n * 50 + k];
            sr[idx & 31] += conn_w[n * 50 + k];
        }
        for (int j = 0; j < 32; ++j) weffT[j * 2500 + n] = sr[j];
    }
}

// ---------------------------------------------------------------------------
// z = (base @ W_eff^T)*sens; a = per-group activation. amat stored bf16
// [b][2528] (K-padded with zeros for the MFMA GEMM).
// ---------------------------------------------------------------------------
__global__ __launch_bounds__(256) void za_kernel(
    const float* __restrict__ base, const float* __restrict__ weffT,
    const float* __restrict__ sens, const float* __restrict__ thr,
    unsigned short* __restrict__ amat)
{
    __shared__ float bs[16][32];
    int tid = threadIdx.x;
    int bb = blockIdx.x / 10, nb = blockIdx.x % 10;
    int n = nb * 256 + tid;
    bool nv = n < 2500;
    bool pv = n < 2528;
    int nn = nv ? n : 0;
    for (int i = tid; i < 512; i += 256) bs[i >> 5][i & 31] = base[bb * 512 + i];
    __syncthreads();
    float w[32];
#pragma unroll
    for (int j = 0; j < 32; ++j) w[j] = weffT[j * 2500 + nn];
    float sn = sens[nn], tn = thr[nn];
    int g = (n < 800) ? 0 : (n < 1500) ? 1 : (n < 2100) ? 2 : 3;
#pragma unroll 2
    for (int r = 0; r < 16; ++r) {
        float z = 0.f;
#pragma unroll
        for (int j = 0; j < 32; ++j) z = fmaf(bs[r][j], w[j], z);
        z *= sn;
        float av;
        if (g == 0)      av = sigf(z - tn);
        else if (g == 1) av = tanhft(z);
        else if (g == 2) av = fmaxf(z - tn, 0.f);
        else             av = sigf(z);
        if (nv)      amat[(bb * 16 + r) * 2528 + n] = f2bf(av);
        else if (pv) amat[(bb * 16 + r) * 2528 + n] = 0;
    }
}

// ---------------------------------------------------------------------------
// t1 = relu(a @ iw1^T + ib1): M=1024 N=256 K=2528(padded), bf16 MFMA.
// R5-verified: grid (8,32) = 256 blocks x 128 thr, 1-deep prefetch.
// ---------------------------------------------------------------------------
__global__ __launch_bounds__(128) void gemm_iw1_kernel(
    const unsigned short* __restrict__ ab, const unsigned short* __restrict__ wb,
    const float* __restrict__ ib1, float* __restrict__ t1)
{
    const int tid = threadIdx.x;
    const int wv  = tid >> 6;
    const int l15 = tid & 15, q = (tid >> 4) & 3, q8 = q * 8;
    const int row0 = blockIdx.y * 32 + wv * 16;
    const int col0 = blockIdx.x * 32;

    const unsigned short* A = ab + (row0 + l15) * 2528 + q8;
    const unsigned short* B = wb + (col0 + l15) * 2528 + q8;

    short8 a = *(const short8*)A;
    short8 b[2];
#pragma unroll
    for (int nt = 0; nt < 2; ++nt) b[nt] = *(const short8*)(B + nt * 16 * 2528);

    f32x4 acc[2];
#pragma unroll
    for (int nt = 0; nt < 2; ++nt) acc[nt] = (f32x4){0.f, 0.f, 0.f, 0.f};

    for (int c = 0; c < 79; ++c) {
        int cn = (c < 78) ? c + 1 : 78;
        short8 an = *(const short8*)(A + cn * 32);
        short8 bn[2];
#pragma unroll
        for (int nt = 0; nt < 2; ++nt)
            bn[nt] = *(const short8*)(B + nt * 16 * 2528 + cn * 32);
#pragma unroll
        for (int nt = 0; nt < 2; ++nt)
            acc[nt] = __builtin_amdgcn_mfma_f32_16x16x32_bf16(a, b[nt], acc[nt], 0, 0, 0);
        a = an;
#pragma unroll
        for (int nt = 0; nt < 2; ++nt) b[nt] = bn[nt];
    }

#pragma unroll
    for (int nt = 0; nt < 2; ++nt) {
        int n = col0 + nt * 16 + l15;
        float bias = ib1[n];
#pragma unroll
        for (int i = 0; i < 4; ++i) {
            int row = row0 + q * 4 + i;
            t1[row * 256 + n] = fmaxf(acc[nt][i] + bias, 0.f);
        }
    }
}

// ---------------------------------------------------------------------------
// final v2 (R5-verified): t2 = relu(t1@iw2^T+ib2); integ = tanh(t2@iw3^T+ib3);
// heads. 256 blocks x 256 thr, iw2/iw3 LDS-staged (257/65 padding).
// ---------------------------------------------------------------------------
__global__ __launch_bounds__(256) void final_kernel(
    const float* __restrict__ t1, const float* __restrict__ iw2,
    const float* __restrict__ ib2, const float* __restrict__ iw3,
    const float* __restrict__ ib3,
    const float* __restrict__ hw_trend, const float* __restrict__ hb_trend,
    const float* __restrict__ hw_pat,   const float* __restrict__ hb_pat,
    const float* __restrict__ hw_key,   const float* __restrict__ hb_key,
    const float* __restrict__ hw_vol,   const float* __restrict__ hb_vol,
    const float* __restrict__ hw_conf,  const float* __restrict__ hb_conf,
    float* __restrict__ out)
{
    __shared__ float iw2s[64 * 257];
    __shared__ float iw3s[32 * 65];
    __shared__ float t1s[4][256];
    __shared__ float t2s[4][64];
    __shared__ float igs[4][32];

    const int tid = threadIdx.x;
    const int b0  = blockIdx.x * 4;

    for (int i = tid; i < 16384; i += 256) {
        int u = i >> 8, k = i & 255;
        iw2s[u * 257 + k] = iw2[i];
    }
    for (int i = tid; i < 2048; i += 256) {
        int u = i >> 6, k = i & 63;
        iw3s[u * 65 + k] = iw3[i];
    }
    for (int i = tid; i < 1024; i += 256)
        t1s[i >> 8][i & 255] = t1[b0 * 256 + i];
    __syncthreads();

    {
        const int r = tid >> 6, u = tid & 63;
        float acc = ib2[u];
        const float* wr = &iw2s[u * 257];
        const float* tr = &t1s[r][0];
#pragma unroll 4
        for (int k = 0; k < 256; ++k) acc = fmaf(tr[k], wr[k], acc);
        t2s[r][u] = fmaxf(acc, 0.f);
    }
    __syncthreads();

    if (tid < 128) {
        const int r = tid >> 5, u2 = tid & 31;
        float a2 = ib3[u2];
        const float* wr = &iw3s[u2 * 65];
        const float* tr = &t2s[r][0];
#pragma unroll 4
        for (int k = 0; k < 64; ++k) a2 = fmaf(tr[k], wr[k], a2);
        igs[r][u2] = tanhft(a2);
    }
    __syncthreads();

    if (tid < 60) {
        const int r = tid / 15, t15 = tid % 15;
        const int b = b0 + r;
        const float* w; const float* bb; int j, off;
        if (t15 < 3)        { w = hw_trend; bb = hb_trend; j = t15;     off = 0; }
        else if (t15 < 9)   { w = hw_pat;   bb = hb_pat;   j = t15 - 3; off = 3; }
        else if (t15 < 13)  { w = hw_key;   bb = hb_key;   j = t15 - 9; off = 9; }
        else if (t15 == 13) { w = hw_vol;   bb = hb_vol;   j = 0;       off = 13; }
        else                { w = hw_conf;  bb = hb_conf;  j = 0;       off = 14; }
        float a3 = bb[j];
#pragma unroll
        for (int k = 0; k < 32; ++k) a3 = fmaf(igs[r][k], w[j * 32 + k], a3);
        out[b * 20 + off + j] = a3;
        if (t15 == 14) out[b * 20 + 15] = sigf(a3);
    }
}

// ---------------------------------------------------------------------------
// group means of a (bf16, padded pitch 2528) -> out[:, 16:20]
// ---------------------------------------------------------------------------
__global__ __launch_bounds__(256) void means_kernel(
    const unsigned short* __restrict__ amat, float* __restrict__ out)
{
    __shared__ float red[16];
    int b = blockIdx.x, tid = threadIdx.x;
    float parts[4] = {0.f, 0.f, 0.f, 0.f};
    for (int n0 = tid * 8; n0 < 2500; n0 += 2048) {
        short8 v = *(const short8*)(amat + b * 2528 + n0);
#pragma unroll
        for (int e = 0; e < 8; ++e) {
            int n = n0 + e;
            float f = bf2f((unsigned short)v[e]);
            if (n < 800)       parts[0] += f;
            else if (n < 1500) parts[1] += f;
            else if (n < 2100) parts[2] += f;
            else               parts[3] += f;   // n in [2500,2528) pad adds 0
        }
    }
    int lane = tid & 63, wv = tid >> 6;
#pragma unroll
    for (int g = 0; g < 4; ++g) {
        float v = parts[g];
        for (int s = 32; s > 0; s >>= 1) v += __shfl_down(v, s, 64);
        if (lane == 0) red[wv * 4 + g] = v;
    }
    __syncthreads();
    if (tid < 4) {
        float s = red[tid] + red[4 + tid] + red[8 + tid] + red[12 + tid];
        float invg = (tid == 0) ? (1.f / 800.f) : (tid == 1) ? (1.f / 700.f)
                   : (tid == 2) ? (1.f / 600.f) : (1.f / 400.f);
        out[b * 20 + 16 + tid] = s * invg;
    }
}

// ---------------------------------------------------------------------------
extern "C" void kernel_launch(void* const* d_in, const int* in_sizes, int n_in,
                              void* d_out, int out_size, void* d_ws, size_t ws_size,
                              hipStream_t stream)
{
    const float* x        = (const float*)d_in[0];
    const int*   conn_idx = (const int*)  d_in[1];
    const float* w_ih0    = (const float*)d_in[2];
    const float* w_hh0    = (const float*)d_in[3];
    const float* b_ih0    = (const float*)d_in[4];
    const float* b_hh0    = (const float*)d_in[5];
    const float* w_ih1    = (const float*)d_in[6];
    const float* w_hh1    = (const float*)d_in[7];
    const float* b_ih1    = (const float*)d_in[8];
    const float* b_hh1    = (const float*)d_in[9];
    const float* pw1      = (const float*)d_in[10];
    const float* pb1      = (const float*)d_in[11];
    const float* pw2      = (const float*)d_in[12];
    const float* pb2      = (const float*)d_in[13];
    const float* conn_w   = (const float*)d_in[14];
    const float* sens     = (const float*)d_in[15];
    const float* thr      = (const float*)d_in[16];
    const float* iw1      = (const float*)d_in[17];
    const float* ib1      = (const float*)d_in[18];
    const float* iw2      = (const float*)d_in[19];
    const float* ib2      = (const float*)d_in[20];
    const float* iw3      = (const float*)d_in[21];
    const float* ib3      = (const float*)d_in[22];
    const float* hw_trend = (const float*)d_in[23];
    const float* hb_trend = (const float*)d_in[24];
    const float* hw_pat   = (const float*)d_in[25];
    const float* hb_pat   = (const float*)d_in[26];
    const float* hw_key   = (const float*)d_in[27];
    const float* hb_key   = (const float*)d_in[28];
    const float* hw_vol   = (const float*)d_in[29];
    const float* hb_vol   = (const float*)d_in[30];
    const float* hw_conf  = (const float*)d_in[31];
    const float* hb_conf  = (const float*)d_in[32];
    float* out = (float*)d_out;
    float* ws  = (float*)d_ws;

    // ws layout (float slots)
    unsigned short* whh0h = (unsigned short*)(ws);           // 32768 f
    unsigned short* wih1h = (unsigned short*)(ws + 32768);   // 32768 f
    unsigned short* whh1h = (unsigned short*)(ws + 65536);   // 32768 f
    float* bias0  = ws + 98304;   // 512
    float* bias1  = ws + 98816;   // 512
    float* h2     = ws + 99328;   // 131072
    float* base_  = ws + 230400;  // 32768
    float* weffT  = ws + 263168;  // 80000
    float* t1     = ws + 343168;  // 262144
    unsigned short* iw1b   = (unsigned short*)(ws + 605312); // 323584 f
    unsigned short* amatbf = (unsigned short*)(ws + 928896); // 1294336 f -> ends 2223232

    prep_kernel<<<258, 256, 0, stream>>>(w_hh0, w_ih1, w_hh1,
                                         b_ih0, b_hh0, b_ih1, b_hh1,
                                         whh0h, wih1h, whh1h, bias0, bias1);
    prep_iw1_kernel<<<2528, 256, 0, stream>>>(iw1, iw1b);
    lstm_kernel<<<512, 512, 0, stream>>>(x, whh0h, wih1h, whh1h, w_ih0,
                                         bias0, bias1, h2);
    phase2_kernel<<<256, 256, 0, stream>>>(h2, pw1, pb1, pw2, pb2, base_);
    weff_kernel<<<20, 128, 0, stream>>>(conn_idx, conn_w, weffT);
    za_kernel<<<640, 256, 0, stream>>>(base_, weffT, sens, thr, amatbf);
    gemm_iw1_kernel<<<dim3(8, 32), 128, 0, stream>>>(amatbf, iw1b, ib1, t1);
    final_kernel<<<256, 256, 0, stream>>>(t1, iw2, ib2, iw3, ib3,
                                          hw_trend, hb_trend, hw_pat, hb_pat,
                                          hw_key, hb_key, hw_vol, hb_vol,
                                          hw_conf, hb_conf, out);
    means_kernel<<<1024, 256, 0, stream>>>(amatbf, out);
}

// Round 10
// 291.324 us; speedup vs baseline: 3.9620x; 1.3882x over previous
//
#include <hip/hip_runtime.h>
#include <hip/hip_bf16.h>
#include <math.h>

#define DEV __device__ __forceinline__

typedef short short8 __attribute__((ext_vector_type(8)));
typedef float f32x4  __attribute__((ext_vector_type(4)));

DEV float sigf(float x)   { return 1.0f / (1.0f + __expf(-x)); }
DEV float tanhft(float x) { return 1.0f - 2.0f / (__expf(2.0f * x) + 1.0f); }

// float -> bf16 (round to nearest even), as raw u16
DEV unsigned short f2bf(float f) {
    unsigned int u = __float_as_uint(f);
    unsigned int r = (u + 0x7FFFu + ((u >> 16) & 1u)) >> 16;
    return (unsigned short)r;
}
DEV float bf2f(unsigned short u) {
    return __uint_as_float(((unsigned int)u) << 16);
}

// LDS-only barrier: drain LDS ops but leave global loads (vmcnt) in flight.
DEV void bar_lds() {
    asm volatile("s_waitcnt lgkmcnt(0)" ::: "memory");
    __builtin_amdgcn_s_barrier();
}

// ---------------------------------------------------------------------------
// prep (blocks 0..257): recurrent weights -> bf16, bias sums.
// weff (blocks 258..277): W_eff^T[j][n] = sum_{k: conn_idx[n,k]%32==j}
// conn_w[n,k]. Independent of prep's outputs (reads only kernel inputs), so
// fusing into one launch is hazard-free; the 20 latency-bound weff blocks
// run concurrently with prep's 258 BW-bound blocks instead of serializing
// as a separate dispatch.
// ---------------------------------------------------------------------------
__global__ __launch_bounds__(256) void prep_kernel(
    const float* __restrict__ w_hh0, const float* __restrict__ w_ih1,
    const float* __restrict__ w_hh1,
    const float* __restrict__ b_ih0, const float* __restrict__ b_hh0,
    const float* __restrict__ b_ih1, const float* __restrict__ b_hh1,
    const int* __restrict__ conn_idx, const float* __restrict__ conn_w,
    unsigned short* __restrict__ whh0h, unsigned short* __restrict__ wih1h,
    unsigned short* __restrict__ whh1h,
    float* __restrict__ bias0, float* __restrict__ bias1,
    float* __restrict__ weffT)
{
    __shared__ float s[128 * 33];
    if (blockIdx.x < 258) {
        int i = blockIdx.x * 256 + threadIdx.x;
        if (i < 65536) {
            whh0h[i] = f2bf(w_hh0[i]);
            wih1h[i] = f2bf(w_ih1[i]);
            whh1h[i] = f2bf(w_hh1[i]);
        } else if (i < 66048) {
            int c = i - 65536;
            bias0[c] = b_ih0[c] + b_hh0[c];
            bias1[c] = b_ih1[c] + b_hh1[c];
        }
    } else {
        int tid = threadIdx.x;
        if (tid < 128) {
            int n = (blockIdx.x - 258) * 128 + tid;
            float* sr = &s[tid * 33];
#pragma unroll
            for (int j = 0; j < 32; ++j) sr[j] = 0.f;
            if (n < 2500) {
                for (int k = 0; k < 50; ++k) {
                    int idx = conn_idx[n * 50 + k];
                    sr[idx & 31] += conn_w[n * 50 + k];
                }
                for (int j = 0; j < 32; ++j) weffT[j * 2500 + n] = sr[j];
            }
        }
    }
}

// prep iw1 -> bf16 [256][2528], zero-padded K 2500..2527
__global__ __launch_bounds__(256) void prep_iw1_kernel(
    const float* __restrict__ iw1, unsigned short* __restrict__ iw1b)
{
    int i = blockIdx.x * 256 + threadIdx.x;
    if (i < 256 * 2528) {
        int row = i / 2528, k = i - row * 2528;
        iw1b[i] = (k < 2500) ? f2bf(iw1[row * 2500 + k]) : (unsigned short)0;
    }
}

// ---------------------------------------------------------------------------
// MFMA LSTM — R4/R5-verified (131 us): ONE barrier/step, per-wave wsc
// redistribute, w_hh0/w_ih1 resident, w_hh1 streamed with split prefetch
// (vmcnt in flight across bar_lds). 4 rows/block, grid 256, 1 block/CU.
// STRUCTURAL FLOOR — measured evidence:
//  * 2 blocks/CU (R9): w_hh1 L2 stream is per-block -> duplicates to
//    ~49 B/cyc/CU ~= L2 ceiling; 249 us for identical per-CU work.
//  * register-resident w_hh1: spills (R3: WRITE 12MB; R7: 25MB) or is
//    silently sunk by the allocator (R2 == R0 codegen).
//  * LDS-resident w_hh1 (R1): moves stream onto the barrier-drained LDS
//    pipe; 176 us. All exits blocked -> do not touch this kernel.
// ---------------------------------------------------------------------------
__global__ __launch_bounds__(512, 2) void lstm_kernel(
    const float* __restrict__ x,
    const unsigned short* __restrict__ whh0,
    const unsigned short* __restrict__ wih1,
    const unsigned short* __restrict__ whh1,
    const float* __restrict__ wih0,
    const float* __restrict__ bias0, const float* __restrict__ bias1,
    float* __restrict__ h2out)
{
    __shared__ __align__(16) float          xs[4][304];
    __shared__ __align__(16) unsigned short h0s[2][16][136];
    __shared__ __align__(16) unsigned short h1s[2][16][136];
    __shared__ __align__(16) float          wsc[8][4][16][4]; // [wave][g][col][row]
    __shared__ float wih0s[2560];

    const int tid = threadIdx.x;
    const int b0  = blockIdx.x * 4;
    const int l15 = tid & 15;          // MFMA A-row / C-col lane index
    const int q   = (tid >> 4) & 3;    // lane quad == owned batch row
    const int w   = tid >> 6;          // wave 0..7
    const int j   = w * 16 + l15;      // owned hidden unit 0..127
    const int q8  = q * 8;

    // ---- stage x (4 rows), w_ih0; zero h buffers (rows 4..15 stay zero)
    for (int i = tid; i < 1200; i += 512) {
        int m = i / 300, kk = i - m * 300;
        xs[m][kk] = x[(b0 + m) * 300 + kk];
    }
    for (int i = tid; i < 2560; i += 512) wih0s[i] = wih0[i];
    for (int i = tid; i < 2176; i += 512) {
        ((unsigned int*)h0s)[i] = 0u;
        ((unsigned int*)h1s)[i] = 0u;
    }

    // ---- per-lane biases for unit j (loop-invariant, 8 regs)
    float ub0[4], ub1[4];
#pragma unroll
    for (int g = 0; g < 4; ++g) {
        ub0[g] = bias0[g * 128 + j];
        ub1[g] = bias1[g * 128 + j];
    }

    // ---- resident B-fragments: w_hh0, w_ih1 (w_hh1 is streamed)
    short8 bh0[4][4], b1i[4][4];
#pragma unroll
    for (int g = 0; g < 4; ++g)
#pragma unroll
        for (int kc = 0; kc < 4; ++kc) {
            int off = (g * 128 + j) * 128 + kc * 32 + q8;
            bh0[g][kc] = *(const short8*)(whh0 + off);
            b1i[g][kc] = *(const short8*)(wih1 + off);
        }

    float c0 = 0.f, c1 = 0.f, hl = 0.f;
    __syncthreads();

    const unsigned short* wsb = whh1 + j * 128 + q8;  // per-lane stream base

    for (int t = 0; t < 60; ++t) {
        const int p = t & 1;

        // ---- prefetch streamed w_hh1, first half (in flight across BAR)
        short8 wsv[4][4];
#pragma unroll
        for (int g = 0; g < 4; ++g) {
            wsv[g][0] = *(const short8*)(wsb + g * 16384);
            wsv[g][1] = *(const short8*)(wsb + g * 16384 + 32);
        }

        // ================= phase A: layer 0 =================
        f32x4 acc[4];
#pragma unroll
        for (int g = 0; g < 4; ++g) acc[g] = (f32x4){0.f, 0.f, 0.f, 0.f};
        short8 af[4];
#pragma unroll
        for (int kc = 0; kc < 4; ++kc)
            af[kc] = *(const short8*)&h0s[p][l15][kc * 32 + q8];
#pragma unroll
        for (int kc = 0; kc < 4; ++kc)
#pragma unroll
            for (int g = 0; g < 4; ++g)
                acc[g] = __builtin_amdgcn_mfma_f32_16x16x32_bf16(af[kc], bh0[g][kc], acc[g], 0, 0, 0);

        // ---- prefetch streamed w_hh1, second half
#pragma unroll
        for (int g = 0; g < 4; ++g) {
            wsv[g][2] = *(const short8*)(wsb + g * 16384 + 64);
            wsv[g][3] = *(const short8*)(wsb + g * 16384 + 96);
        }

        // intra-wave redistribute: q==0 lanes publish rows 0..3 of 16 cols
        if (q == 0) {
#pragma unroll
            for (int g = 0; g < 4; ++g)
                *(f32x4*)&wsc[w][g][l15][0] = acc[g];
        }
        // each lane picks up (row=q, unit=j); lgkmcnt orders intra-wave
        {
            const float* xr = &xs[q][t * 5];
            float x0 = xr[0], x1 = xr[1], x2 = xr[2], x3 = xr[3], x4 = xr[4];
            float gv[4];
#pragma unroll
            for (int g = 0; g < 4; ++g) {
                const float* wr = &wih0s[(g * 128 + j) * 5];
                float s = wsc[w][g][l15][q] + ub0[g];
                s = fmaf(x0, wr[0], s);
                s = fmaf(x1, wr[1], s);
                s = fmaf(x2, wr[2], s);
                s = fmaf(x3, wr[3], s);
                gv[g] = fmaf(x4, wr[4], s);
            }
            c0 = sigf(gv[1]) * c0 + sigf(gv[0]) * tanhft(gv[2]);
            float h = sigf(gv[3]) * tanhft(c0);
            h0s[1 - p][q][j] = f2bf(h);
        }

        bar_lds();  // the ONLY barrier per step

        // ================= phase B: layer 1 =================
#pragma unroll
        for (int g = 0; g < 4; ++g) acc[g] = (f32x4){0.f, 0.f, 0.f, 0.f};
#pragma unroll
        for (int kc = 0; kc < 4; ++kc)
            af[kc] = *(const short8*)&h0s[1 - p][l15][kc * 32 + q8];
#pragma unroll
        for (int kc = 0; kc < 4; ++kc)
#pragma unroll
            for (int g = 0; g < 4; ++g)
                acc[g] = __builtin_amdgcn_mfma_f32_16x16x32_bf16(af[kc], b1i[g][kc], acc[g], 0, 0, 0);
#pragma unroll
        for (int kc = 0; kc < 4; ++kc)
            af[kc] = *(const short8*)&h1s[p][l15][kc * 32 + q8];
#pragma unroll
        for (int kc = 0; kc < 4; ++kc)
#pragma unroll
            for (int g = 0; g < 4; ++g)
                acc[g] = __builtin_amdgcn_mfma_f32_16x16x32_bf16(af[kc], wsv[g][kc], acc[g], 0, 0, 0);

        if (q == 0) {
#pragma unroll
            for (int g = 0; g < 4; ++g)
                *(f32x4*)&wsc[w][g][l15][0] = acc[g];
        }
        {
            float gv[4];
#pragma unroll
            for (int g = 0; g < 4; ++g)
                gv[g] = wsc[w][g][l15][q] + ub1[g];
            c1 = sigf(gv[1]) * c1 + sigf(gv[0]) * tanhft(gv[2]);
            float h = sigf(gv[3]) * tanhft(c1);
            h1s[1 - p][q][j] = f2bf(h);
            hl = h;
        }
        // no barrier: next step's bar_lds covers h1/h0/wsc hazards
    }

    h2out[(b0 + q) * 128 + j] = hl;
}

// ---------------------------------------------------------------------------
// phase2 v2 (R5-verified): base = tanh(relu(h2 @ pw1^T + pb1) @ pw2^T + pb2).
// ---------------------------------------------------------------------------
__global__ __launch_bounds__(256) void phase2_kernel(
    const float* __restrict__ h2, const float* __restrict__ pw1,
    const float* __restrict__ pb1, const float* __restrict__ pw2,
    const float* __restrict__ pb2, float* __restrict__ base)
{
    __shared__ float pw1s[64 * 129];
    __shared__ float pw2s[32 * 65];
    __shared__ float hs[4][128];
    __shared__ float p1s[4][64];

    const int tid = threadIdx.x;
    const int b0  = blockIdx.x * 4;

    for (int i = tid; i < 8192; i += 256) {
        int u = i >> 7, k = i & 127;
        pw1s[u * 129 + k] = pw1[i];
    }
    for (int i = tid; i < 2048; i += 256) {
        int u = i >> 6, k = i & 63;
        pw2s[u * 65 + k] = pw2[i];
    }
    for (int i = tid; i < 512; i += 256)
        hs[i >> 7][i & 127] = h2[b0 * 128 + i];
    __syncthreads();

    {
        const int r = tid >> 6, u = tid & 63;
        float acc = pb1[u];
        const float* wr = &pw1s[u * 129];
        const float* hr = &hs[r][0];
#pragma unroll 4
        for (int k = 0; k < 128; ++k) acc = fmaf(hr[k], wr[k], acc);
        p1s[r][u] = fmaxf(acc, 0.f);
    }
    __syncthreads();

    if (tid < 128) {
        const int r = tid >> 5, u2 = tid & 31;
        float a2 = pb2[u2];
        const float* wr = &pw2s[u2 * 65];
        const float* pr = &p1s[r][0];
#pragma unroll 4
        for (int k = 0; k < 64; ++k) a2 = fmaf(pr[k], wr[k], a2);
        base[(b0 + r) * 32 + u2] = tanhft(a2);
    }
}

// ---------------------------------------------------------------------------
// z = (base @ W_eff^T)*sens; a = per-group activation. amat stored bf16
// [b][2528] (K-padded with zeros for the MFMA GEMM).
// ---------------------------------------------------------------------------
__global__ __launch_bounds__(256) void za_kernel(
    const float* __restrict__ base, const float* __restrict__ weffT,
    const float* __restrict__ sens, const float* __restrict__ thr,
    unsigned short* __restrict__ amat)
{
    __shared__ float bs[16][32];
    int tid = threadIdx.x;
    int bb = blockIdx.x / 10, nb = blockIdx.x % 10;
    int n = nb * 256 + tid;
    bool nv = n < 2500;
    bool pv = n < 2528;
    int nn = nv ? n : 0;
    for (int i = tid; i < 512; i += 256) bs[i >> 5][i & 31] = base[bb * 512 + i];
    __syncthreads();
    float w[32];
#pragma unroll
    for (int j = 0; j < 32; ++j) w[j] = weffT[j * 2500 + nn];
    float sn = sens[nn], tn = thr[nn];
    int g = (n < 800) ? 0 : (n < 1500) ? 1 : (n < 2100) ? 2 : 3;
#pragma unroll 2
    for (int r = 0; r < 16; ++r) {
        float z = 0.f;
#pragma unroll
        for (int j = 0; j < 32; ++j) z = fmaf(bs[r][j], w[j], z);
        z *= sn;
        float av;
        if (g == 0)      av = sigf(z - tn);
        else if (g == 1) av = tanhft(z);
        else if (g == 2) av = fmaxf(z - tn, 0.f);
        else             av = sigf(z);
        if (nv)      amat[(bb * 16 + r) * 2528 + n] = f2bf(av);
        else if (pv) amat[(bb * 16 + r) * 2528 + n] = 0;
    }
}

// ---------------------------------------------------------------------------
// t1 = relu(a @ iw1^T + ib1): M=1024 N=256 K=2528(padded), bf16 MFMA.
// R5-verified: grid (8,32) = 256 blocks x 128 thr, 1-deep prefetch.
// ---------------------------------------------------------------------------
__global__ __launch_bounds__(128) void gemm_iw1_kernel(
    const unsigned short* __restrict__ ab, const unsigned short* __restrict__ wb,
    const float* __restrict__ ib1, float* __restrict__ t1)
{
    const int tid = threadIdx.x;
    const int wv  = tid >> 6;
    const int l15 = tid & 15, q = (tid >> 4) & 3, q8 = q * 8;
    const int row0 = blockIdx.y * 32 + wv * 16;
    const int col0 = blockIdx.x * 32;

    const unsigned short* A = ab + (row0 + l15) * 2528 + q8;
    const unsigned short* B = wb + (col0 + l15) * 2528 + q8;

    short8 a = *(const short8*)A;
    short8 b[2];
#pragma unroll
    for (int nt = 0; nt < 2; ++nt) b[nt] = *(const short8*)(B + nt * 16 * 2528);

    f32x4 acc[2];
#pragma unroll
    for (int nt = 0; nt < 2; ++nt) acc[nt] = (f32x4){0.f, 0.f, 0.f, 0.f};

    for (int c = 0; c < 79; ++c) {
        int cn = (c < 78) ? c + 1 : 78;
        short8 an = *(const short8*)(A + cn * 32);
        short8 bn[2];
#pragma unroll
        for (int nt = 0; nt < 2; ++nt)
            bn[nt] = *(const short8*)(B + nt * 16 * 2528 + cn * 32);
#pragma unroll
        for (int nt = 0; nt < 2; ++nt)
            acc[nt] = __builtin_amdgcn_mfma_f32_16x16x32_bf16(a, b[nt], acc[nt], 0, 0, 0);
        a = an;
#pragma unroll
        for (int nt = 0; nt < 2; ++nt) b[nt] = bn[nt];
    }

#pragma unroll
    for (int nt = 0; nt < 2; ++nt) {
        int n = col0 + nt * 16 + l15;
        float bias = ib1[n];
#pragma unroll
        for (int i = 0; i < 4; ++i) {
            int row = row0 + q * 4 + i;
            t1[row * 256 + n] = fmaxf(acc[nt][i] + bias, 0.f);
        }
    }
}

// ---------------------------------------------------------------------------
// final v2 (R5-verified): t2 = relu(t1@iw2^T+ib2); integ = tanh(t2@iw3^T+ib3);
// heads. 256 blocks x 256 thr, iw2/iw3 LDS-staged (257/65 padding).
// ---------------------------------------------------------------------------
__global__ __launch_bounds__(256) void final_kernel(
    const float* __restrict__ t1, const float* __restrict__ iw2,
    const float* __restrict__ ib2, const float* __restrict__ iw3,
    const float* __restrict__ ib3,
    const float* __restrict__ hw_trend, const float* __restrict__ hb_trend,
    const float* __restrict__ hw_pat,   const float* __restrict__ hb_pat,
    const float* __restrict__ hw_key,   const float* __restrict__ hb_key,
    const float* __restrict__ hw_vol,   const float* __restrict__ hb_vol,
    const float* __restrict__ hw_conf,  const float* __restrict__ hb_conf,
    float* __restrict__ out)
{
    __shared__ float iw2s[64 * 257];
    __shared__ float iw3s[32 * 65];
    __shared__ float t1s[4][256];
    __shared__ float t2s[4][64];
    __shared__ float igs[4][32];

    const int tid = threadIdx.x;
    const int b0  = blockIdx.x * 4;

    for (int i = tid; i < 16384; i += 256) {
        int u = i >> 8, k = i & 255;
        iw2s[u * 257 + k] = iw2[i];
    }
    for (int i = tid; i < 2048; i += 256) {
        int u = i >> 6, k = i & 63;
        iw3s[u * 65 + k] = iw3[i];
    }
    for (int i = tid; i < 1024; i += 256)
        t1s[i >> 8][i & 255] = t1[b0 * 256 + i];
    __syncthreads();

    {
        const int r = tid >> 6, u = tid & 63;
        float acc = ib2[u];
        const float* wr = &iw2s[u * 257];
        const float* tr = &t1s[r][0];
#pragma unroll 4
        for (int k = 0; k < 256; ++k) acc = fmaf(tr[k], wr[k], acc);
        t2s[r][u] = fmaxf(acc, 0.f);
    }
    __syncthreads();

    if (tid < 128) {
        const int r = tid >> 5, u2 = tid & 31;
        float a2 = ib3[u2];
        const float* wr = &iw3s[u2 * 65];
        const float* tr = &t2s[r][0];
#pragma unroll 4
        for (int k = 0; k < 64; ++k) a2 = fmaf(tr[k], wr[k], a2);
        igs[r][u2] = tanhft(a2);
    }
    __syncthreads();

    if (tid < 60) {
        const int r = tid / 15, t15 = tid % 15;
        const int b = b0 + r;
        const float* w; const float* bb; int j, off;
        if (t15 < 3)        { w = hw_trend; bb = hb_trend; j = t15;     off = 0; }
        else if (t15 < 9)   { w = hw_pat;   bb = hb_pat;   j = t15 - 3; off = 3; }
        else if (t15 < 13)  { w = hw_key;   bb = hb_key;   j = t15 - 9; off = 9; }
        else if (t15 == 13) { w = hw_vol;   bb = hb_vol;   j = 0;       off = 13; }
        else                { w = hw_conf;  bb = hb_conf;  j = 0;       off = 14; }
        float a3 = bb[j];
#pragma unroll
        for (int k = 0; k < 32; ++k) a3 = fmaf(igs[r][k], w[j * 32 + k], a3);
        out[b * 20 + off + j] = a3;
        if (t15 == 14) out[b * 20 + 15] = sigf(a3);
    }
}

// ---------------------------------------------------------------------------
// group means of a (bf16, padded pitch 2528) -> out[:, 16:20]
// ---------------------------------------------------------------------------
__global__ __launch_bounds__(256) void means_kernel(
    const unsigned short* __restrict__ amat, float* __restrict__ out)
{
    __shared__ float red[16];
    int b = blockIdx.x, tid = threadIdx.x;
    float parts[4] = {0.f, 0.f, 0.f, 0.f};
    for (int n0 = tid * 8; n0 < 2500; n0 += 2048) {
        short8 v = *(const short8*)(amat + b * 2528 + n0);
#pragma unroll
        for (int e = 0; e < 8; ++e) {
            int n = n0 + e;
            float f = bf2f((unsigned short)v[e]);
            if (n < 800)       parts[0] += f;
            else if (n < 1500) parts[1] += f;
            else if (n < 2100) parts[2] += f;
            else               parts[3] += f;   // n in [2500,2528) pad adds 0
        }
    }
    int lane = tid & 63, wv = tid >> 6;
#pragma unroll
    for (int g = 0; g < 4; ++g) {
        float v = parts[g];
        for (int s = 32; s > 0; s >>= 1) v += __shfl_down(v, s, 64);
        if (lane == 0) red[wv * 4 + g] = v;
    }
    __syncthreads();
    if (tid < 4) {
        float s = red[tid] + red[4 + tid] + red[8 + tid] + red[12 + tid];
        float invg = (tid == 0) ? (1.f / 800.f) : (tid == 1) ? (1.f / 700.f)
                   : (tid == 2) ? (1.f / 600.f) : (1.f / 400.f);
        out[b * 20 + 16 + tid] = s * invg;
    }
}

// ---------------------------------------------------------------------------
extern "C" void kernel_launch(void* const* d_in, const int* in_sizes, int n_in,
                              void* d_out, int out_size, void* d_ws, size_t ws_size,
                              hipStream_t stream)
{
    const float* x        = (const float*)d_in[0];
    const int*   conn_idx = (const int*)  d_in[1];
    const float* w_ih0    = (const float*)d_in[2];
    const float* w_hh0    = (const float*)d_in[3];
    const float* b_ih0    = (const float*)d_in[4];
    const float* b_hh0    = (const float*)d_in[5];
    const float* w_ih1    = (const float*)d_in[6];
    const float* w_hh1    = (const float*)d_in[7];
    const float* b_ih1    = (const float*)d_in[8];
    const float* b_hh1    = (const float*)d_in[9];
    const float* pw1      = (const float*)d_in[10];
    const float* pb1      = (const float*)d_in[11];
    const float* pw2      = (const float*)d_in[12];
    const float* pb2      = (const float*)d_in[13];
    const float* conn_w   = (const float*)d_in[14];
    const float* sens     = (const float*)d_in[15];
    const float* thr      = (const float*)d_in[16];
    const float* iw1      = (const float*)d_in[17];
    const float* ib1      = (const float*)d_in[18];
    const float* iw2      = (const float*)d_in[19];
    const float* ib2      = (const float*)d_in[20];
    const float* iw3      = (const float*)d_in[21];
    const float* ib3      = (const float*)d_in[22];
    const float* hw_trend = (const float*)d_in[23];
    const float* hb_trend = (const float*)d_in[24];
    const float* hw_pat   = (const float*)d_in[25];
    const float* hb_pat   = (const float*)d_in[26];
    const float* hw_key   = (const float*)d_in[27];
    const float* hb_key   = (const float*)d_in[28];
    const float* hw_vol   = (const float*)d_in[29];
    const float* hb_vol   = (const float*)d_in[30];
    const float* hw_conf  = (const float*)d_in[31];
    const float* hb_conf  = (const float*)d_in[32];
    float* out = (float*)d_out;
    float* ws  = (float*)d_ws;

    // ws layout (float slots)
    unsigned short* whh0h = (unsigned short*)(ws);           // 32768 f
    unsigned short* wih1h = (unsigned short*)(ws + 32768);   // 32768 f
    unsigned short* whh1h = (unsigned short*)(ws + 65536);   // 32768 f
    float* bias0  = ws + 98304;   // 512
    float* bias1  = ws + 98816;   // 512
    float* h2     = ws + 99328;   // 131072
    float* base_  = ws + 230400;  // 32768
    float* weffT  = ws + 263168;  // 80000
    float* t1     = ws + 343168;  // 262144
    unsigned short* iw1b   = (unsigned short*)(ws + 605312); // 323584 f
    unsigned short* amatbf = (unsigned short*)(ws + 928896); // 1294336 f -> ends 2223232

    prep_kernel<<<278, 256, 0, stream>>>(w_hh0, w_ih1, w_hh1,
                                         b_ih0, b_hh0, b_ih1, b_hh1,
                                         conn_idx, conn_w,
                                         whh0h, wih1h, whh1h, bias0, bias1,
                                         weffT);
    prep_iw1_kernel<<<2528, 256, 0, stream>>>(iw1, iw1b);
    lstm_kernel<<<256, 512, 0, stream>>>(x, whh0h, wih1h, whh1h, w_ih0,
                                         bias0, bias1, h2);
    phase2_kernel<<<256, 256, 0, stream>>>(h2, pw1, pb1, pw2, pb2, base_);
    za_kernel<<<640, 256, 0, stream>>>(base_, weffT, sens, thr, amatbf);
    gemm_iw1_kernel<<<dim3(8, 32), 128, 0, stream>>>(amatbf, iw1b, ib1, t1);
    final_kernel<<<256, 256, 0, stream>>>(t1, iw2, ib2, iw3, ib3,
                                          hw_trend, hb_trend, hw_pat, hb_pat,
                                          hw_key, hb_key, hw_vol, hb_vol,
                                          hw_conf, hb_conf, out);
    means_kernel<<<1024, 256, 0, stream>>>(amatbf, out);
}

// Round 11
// 286.380 us; speedup vs baseline: 4.0304x; 1.0173x over previous
//
#include <hip/hip_runtime.h>
#include <hip/hip_bf16.h>
#include <math.h>

#define DEV __device__ __forceinline__

typedef short short8 __attribute__((ext_vector_type(8)));
typedef float f32x4  __attribute__((ext_vector_type(4)));

DEV float sigf(float x)   { return 1.0f / (1.0f + __expf(-x)); }
DEV float tanhft(float x) { return 1.0f - 2.0f / (__expf(2.0f * x) + 1.0f); }

// float -> bf16 (round to nearest even), as raw u16
DEV unsigned short f2bf(float f) {
    unsigned int u = __float_as_uint(f);
    unsigned int r = (u + 0x7FFFu + ((u >> 16) & 1u)) >> 16;
    return (unsigned short)r;
}
DEV float bf2f(unsigned short u) {
    return __uint_as_float(((unsigned int)u) << 16);
}

// LDS-only barrier: drain LDS ops but leave global loads (vmcnt) in flight.
DEV void bar_lds() {
    asm volatile("s_waitcnt lgkmcnt(0)" ::: "memory");
    __builtin_amdgcn_s_barrier();
}

// ---------------------------------------------------------------------------
// prep_all — one launch, three independent jobs (measured ~3.5 us per
// deleted dispatch, R10):
//   blocks 0..257    : recurrent weights -> bf16, bias sums (R0-verified)
//   blocks 258..277  : weff  W_eff^T[j][n] = sum_{k: idx%32==j} w (R10-verified)
//   blocks 278..2805 : iw1 -> bf16 [256][2528], K-padded (R6-verified)
// All three read only kernel inputs and write disjoint buffers.
// ---------------------------------------------------------------------------
__global__ __launch_bounds__(256) void prep_all_kernel(
    const float* __restrict__ w_hh0, const float* __restrict__ w_ih1,
    const float* __restrict__ w_hh1,
    const float* __restrict__ b_ih0, const float* __restrict__ b_hh0,
    const float* __restrict__ b_ih1, const float* __restrict__ b_hh1,
    const int* __restrict__ conn_idx, const float* __restrict__ conn_w,
    const float* __restrict__ iw1,
    unsigned short* __restrict__ whh0h, unsigned short* __restrict__ wih1h,
    unsigned short* __restrict__ whh1h,
    float* __restrict__ bias0, float* __restrict__ bias1,
    float* __restrict__ weffT, unsigned short* __restrict__ iw1b)
{
    __shared__ float s[128 * 33];
    const int blk = blockIdx.x;
    if (blk < 258) {
        int i = blk * 256 + threadIdx.x;
        if (i < 65536) {
            whh0h[i] = f2bf(w_hh0[i]);
            wih1h[i] = f2bf(w_ih1[i]);
            whh1h[i] = f2bf(w_hh1[i]);
        } else if (i < 66048) {
            int c = i - 65536;
            bias0[c] = b_ih0[c] + b_hh0[c];
            bias1[c] = b_ih1[c] + b_hh1[c];
        }
    } else if (blk < 278) {
        int tid = threadIdx.x;
        if (tid < 128) {
            int n = (blk - 258) * 128 + tid;
            float* sr = &s[tid * 33];
#pragma unroll
            for (int j = 0; j < 32; ++j) sr[j] = 0.f;
            if (n < 2500) {
                for (int k = 0; k < 50; ++k) {
                    int idx = conn_idx[n * 50 + k];
                    sr[idx & 31] += conn_w[n * 50 + k];
                }
                for (int j = 0; j < 32; ++j) weffT[j * 2500 + n] = sr[j];
            }
        }
    } else {
        int i = (blk - 278) * 256 + threadIdx.x;
        if (i < 256 * 2528) {
            int row = i / 2528, k = i - row * 2528;
            iw1b[i] = (k < 2500) ? f2bf(iw1[row * 2500 + k]) : (unsigned short)0;
        }
    }
}

// ---------------------------------------------------------------------------
// MFMA LSTM — R4/R5-verified (131 us): ONE barrier/step, per-wave wsc
// redistribute, w_hh0/w_ih1 resident, w_hh1 streamed with split prefetch
// (vmcnt in flight across bar_lds). 4 rows/block, grid 256, 1 block/CU.
// STRUCTURAL FLOOR — measured evidence:
//  * 2 blocks/CU (R9): w_hh1 L2 stream is per-block -> duplicates to
//    ~49 B/cyc/CU ~= L2 ceiling; 249 us for identical per-CU work.
//  * register-resident w_hh1: spills (R3: WRITE 12MB; R7: 25MB) or is
//    silently sunk by the allocator (R2 == R0 codegen).
//  * LDS-resident w_hh1 (R1): moves stream onto the barrier-drained LDS
//    pipe; 176 us. All exits blocked -> do not touch this kernel.
// ---------------------------------------------------------------------------
__global__ __launch_bounds__(512, 2) void lstm_kernel(
    const float* __restrict__ x,
    const unsigned short* __restrict__ whh0,
    const unsigned short* __restrict__ wih1,
    const unsigned short* __restrict__ whh1,
    const float* __restrict__ wih0,
    const float* __restrict__ bias0, const float* __restrict__ bias1,
    float* __restrict__ h2out)
{
    __shared__ __align__(16) float          xs[4][304];
    __shared__ __align__(16) unsigned short h0s[2][16][136];
    __shared__ __align__(16) unsigned short h1s[2][16][136];
    __shared__ __align__(16) float          wsc[8][4][16][4]; // [wave][g][col][row]
    __shared__ float wih0s[2560];

    const int tid = threadIdx.x;
    const int b0  = blockIdx.x * 4;
    const int l15 = tid & 15;          // MFMA A-row / C-col lane index
    const int q   = (tid >> 4) & 3;    // lane quad == owned batch row
    const int w   = tid >> 6;          // wave 0..7
    const int j   = w * 16 + l15;      // owned hidden unit 0..127
    const int q8  = q * 8;

    // ---- stage x (4 rows), w_ih0; zero h buffers (rows 4..15 stay zero)
    for (int i = tid; i < 1200; i += 512) {
        int m = i / 300, kk = i - m * 300;
        xs[m][kk] = x[(b0 + m) * 300 + kk];
    }
    for (int i = tid; i < 2560; i += 512) wih0s[i] = wih0[i];
    for (int i = tid; i < 2176; i += 512) {
        ((unsigned int*)h0s)[i] = 0u;
        ((unsigned int*)h1s)[i] = 0u;
    }

    // ---- per-lane biases for unit j (loop-invariant, 8 regs)
    float ub0[4], ub1[4];
#pragma unroll
    for (int g = 0; g < 4; ++g) {
        ub0[g] = bias0[g * 128 + j];
        ub1[g] = bias1[g * 128 + j];
    }

    // ---- resident B-fragments: w_hh0, w_ih1 (w_hh1 is streamed)
    short8 bh0[4][4], b1i[4][4];
#pragma unroll
    for (int g = 0; g < 4; ++g)
#pragma unroll
        for (int kc = 0; kc < 4; ++kc) {
            int off = (g * 128 + j) * 128 + kc * 32 + q8;
            bh0[g][kc] = *(const short8*)(whh0 + off);
            b1i[g][kc] = *(const short8*)(wih1 + off);
        }

    float c0 = 0.f, c1 = 0.f, hl = 0.f;
    __syncthreads();

    const unsigned short* wsb = whh1 + j * 128 + q8;  // per-lane stream base

    for (int t = 0; t < 60; ++t) {
        const int p = t & 1;

        // ---- prefetch streamed w_hh1, first half (in flight across BAR)
        short8 wsv[4][4];
#pragma unroll
        for (int g = 0; g < 4; ++g) {
            wsv[g][0] = *(const short8*)(wsb + g * 16384);
            wsv[g][1] = *(const short8*)(wsb + g * 16384 + 32);
        }

        // ================= phase A: layer 0 =================
        f32x4 acc[4];
#pragma unroll
        for (int g = 0; g < 4; ++g) acc[g] = (f32x4){0.f, 0.f, 0.f, 0.f};
        short8 af[4];
#pragma unroll
        for (int kc = 0; kc < 4; ++kc)
            af[kc] = *(const short8*)&h0s[p][l15][kc * 32 + q8];
#pragma unroll
        for (int kc = 0; kc < 4; ++kc)
#pragma unroll
            for (int g = 0; g < 4; ++g)
                acc[g] = __builtin_amdgcn_mfma_f32_16x16x32_bf16(af[kc], bh0[g][kc], acc[g], 0, 0, 0);

        // ---- prefetch streamed w_hh1, second half
#pragma unroll
        for (int g = 0; g < 4; ++g) {
            wsv[g][2] = *(const short8*)(wsb + g * 16384 + 64);
            wsv[g][3] = *(const short8*)(wsb + g * 16384 + 96);
        }

        // intra-wave redistribute: q==0 lanes publish rows 0..3 of 16 cols
        if (q == 0) {
#pragma unroll
            for (int g = 0; g < 4; ++g)
                *(f32x4*)&wsc[w][g][l15][0] = acc[g];
        }
        // each lane picks up (row=q, unit=j); lgkmcnt orders intra-wave
        {
            const float* xr = &xs[q][t * 5];
            float x0 = xr[0], x1 = xr[1], x2 = xr[2], x3 = xr[3], x4 = xr[4];
            float gv[4];
#pragma unroll
            for (int g = 0; g < 4; ++g) {
                const float* wr = &wih0s[(g * 128 + j) * 5];
                float s = wsc[w][g][l15][q] + ub0[g];
                s = fmaf(x0, wr[0], s);
                s = fmaf(x1, wr[1], s);
                s = fmaf(x2, wr[2], s);
                s = fmaf(x3, wr[3], s);
                gv[g] = fmaf(x4, wr[4], s);
            }
            c0 = sigf(gv[1]) * c0 + sigf(gv[0]) * tanhft(gv[2]);
            float h = sigf(gv[3]) * tanhft(c0);
            h0s[1 - p][q][j] = f2bf(h);
        }

        bar_lds();  // the ONLY barrier per step

        // ================= phase B: layer 1 =================
#pragma unroll
        for (int g = 0; g < 4; ++g) acc[g] = (f32x4){0.f, 0.f, 0.f, 0.f};
#pragma unroll
        for (int kc = 0; kc < 4; ++kc)
            af[kc] = *(const short8*)&h0s[1 - p][l15][kc * 32 + q8];
#pragma unroll
        for (int kc = 0; kc < 4; ++kc)
#pragma unroll
            for (int g = 0; g < 4; ++g)
                acc[g] = __builtin_amdgcn_mfma_f32_16x16x32_bf16(af[kc], b1i[g][kc], acc[g], 0, 0, 0);
#pragma unroll
        for (int kc = 0; kc < 4; ++kc)
            af[kc] = *(const short8*)&h1s[p][l15][kc * 32 + q8];
#pragma unroll
        for (int kc = 0; kc < 4; ++kc)
#pragma unroll
            for (int g = 0; g < 4; ++g)
                acc[g] = __builtin_amdgcn_mfma_f32_16x16x32_bf16(af[kc], wsv[g][kc], acc[g], 0, 0, 0);

        if (q == 0) {
#pragma unroll
            for (int g = 0; g < 4; ++g)
                *(f32x4*)&wsc[w][g][l15][0] = acc[g];
        }
        {
            float gv[4];
#pragma unroll
            for (int g = 0; g < 4; ++g)
                gv[g] = wsc[w][g][l15][q] + ub1[g];
            c1 = sigf(gv[1]) * c1 + sigf(gv[0]) * tanhft(gv[2]);
            float h = sigf(gv[3]) * tanhft(c1);
            h1s[1 - p][q][j] = f2bf(h);
            hl = h;
        }
        // no barrier: next step's bar_lds covers h1/h0/wsc hazards
    }

    h2out[(b0 + q) * 128 + j] = hl;
}

// ---------------------------------------------------------------------------
// phase2 v2 (R5-verified): base = tanh(relu(h2 @ pw1^T + pb1) @ pw2^T + pb2).
// ---------------------------------------------------------------------------
__global__ __launch_bounds__(256) void phase2_kernel(
    const float* __restrict__ h2, const float* __restrict__ pw1,
    const float* __restrict__ pb1, const float* __restrict__ pw2,
    const float* __restrict__ pb2, float* __restrict__ base)
{
    __shared__ float pw1s[64 * 129];
    __shared__ float pw2s[32 * 65];
    __shared__ float hs[4][128];
    __shared__ float p1s[4][64];

    const int tid = threadIdx.x;
    const int b0  = blockIdx.x * 4;

    for (int i = tid; i < 8192; i += 256) {
        int u = i >> 7, k = i & 127;
        pw1s[u * 129 + k] = pw1[i];
    }
    for (int i = tid; i < 2048; i += 256) {
        int u = i >> 6, k = i & 63;
        pw2s[u * 65 + k] = pw2[i];
    }
    for (int i = tid; i < 512; i += 256)
        hs[i >> 7][i & 127] = h2[b0 * 128 + i];
    __syncthreads();

    {
        const int r = tid >> 6, u = tid & 63;
        float acc = pb1[u];
        const float* wr = &pw1s[u * 129];
        const float* hr = &hs[r][0];
#pragma unroll 4
        for (int k = 0; k < 128; ++k) acc = fmaf(hr[k], wr[k], acc);
        p1s[r][u] = fmaxf(acc, 0.f);
    }
    __syncthreads();

    if (tid < 128) {
        const int r = tid >> 5, u2 = tid & 31;
        float a2 = pb2[u2];
        const float* wr = &pw2s[u2 * 65];
        const float* pr = &p1s[r][0];
#pragma unroll 4
        for (int k = 0; k < 64; ++k) a2 = fmaf(pr[k], wr[k], a2);
        base[(b0 + r) * 32 + u2] = tanhft(a2);
    }
}

// ---------------------------------------------------------------------------
// z = (base @ W_eff^T)*sens; a = per-group activation. amat stored bf16
// [b][2528] (K-padded with zeros for the MFMA GEMM).
// ---------------------------------------------------------------------------
__global__ __launch_bounds__(256) void za_kernel(
    const float* __restrict__ base, const float* __restrict__ weffT,
    const float* __restrict__ sens, const float* __restrict__ thr,
    unsigned short* __restrict__ amat)
{
    __shared__ float bs[16][32];
    int tid = threadIdx.x;
    int bb = blockIdx.x / 10, nb = blockIdx.x % 10;
    int n = nb * 256 + tid;
    bool nv = n < 2500;
    bool pv = n < 2528;
    int nn = nv ? n : 0;
    for (int i = tid; i < 512; i += 256) bs[i >> 5][i & 31] = base[bb * 512 + i];
    __syncthreads();
    float w[32];
#pragma unroll
    for (int j = 0; j < 32; ++j) w[j] = weffT[j * 2500 + nn];
    float sn = sens[nn], tn = thr[nn];
    int g = (n < 800) ? 0 : (n < 1500) ? 1 : (n < 2100) ? 2 : 3;
#pragma unroll 2
    for (int r = 0; r < 16; ++r) {
        float z = 0.f;
#pragma unroll
        for (int j = 0; j < 32; ++j) z = fmaf(bs[r][j], w[j], z);
        z *= sn;
        float av;
        if (g == 0)      av = sigf(z - tn);
        else if (g == 1) av = tanhft(z);
        else if (g == 2) av = fmaxf(z - tn, 0.f);
        else             av = sigf(z);
        if (nv)      amat[(bb * 16 + r) * 2528 + n] = f2bf(av);
        else if (pv) amat[(bb * 16 + r) * 2528 + n] = 0;
    }
}

// ---------------------------------------------------------------------------
// t1 = relu(a @ iw1^T + ib1): M=1024 N=256 K=2528(padded), bf16 MFMA.
// R5-verified: grid (8,32) = 256 blocks x 128 thr, 1-deep prefetch.
// ---------------------------------------------------------------------------
__global__ __launch_bounds__(128) void gemm_iw1_kernel(
    const unsigned short* __restrict__ ab, const unsigned short* __restrict__ wb,
    const float* __restrict__ ib1, float* __restrict__ t1)
{
    const int tid = threadIdx.x;
    const int wv  = tid >> 6;
    const int l15 = tid & 15, q = (tid >> 4) & 3, q8 = q * 8;
    const int row0 = blockIdx.y * 32 + wv * 16;
    const int col0 = blockIdx.x * 32;

    const unsigned short* A = ab + (row0 + l15) * 2528 + q8;
    const unsigned short* B = wb + (col0 + l15) * 2528 + q8;

    short8 a = *(const short8*)A;
    short8 b[2];
#pragma unroll
    for (int nt = 0; nt < 2; ++nt) b[nt] = *(const short8*)(B + nt * 16 * 2528);

    f32x4 acc[2];
#pragma unroll
    for (int nt = 0; nt < 2; ++nt) acc[nt] = (f32x4){0.f, 0.f, 0.f, 0.f};

    for (int c = 0; c < 79; ++c) {
        int cn = (c < 78) ? c + 1 : 78;
        short8 an = *(const short8*)(A + cn * 32);
        short8 bn[2];
#pragma unroll
        for (int nt = 0; nt < 2; ++nt)
            bn[nt] = *(const short8*)(B + nt * 16 * 2528 + cn * 32);
#pragma unroll
        for (int nt = 0; nt < 2; ++nt)
            acc[nt] = __builtin_amdgcn_mfma_f32_16x16x32_bf16(a, b[nt], acc[nt], 0, 0, 0);
        a = an;
#pragma unroll
        for (int nt = 0; nt < 2; ++nt) b[nt] = bn[nt];
    }

#pragma unroll
    for (int nt = 0; nt < 2; ++nt) {
        int n = col0 + nt * 16 + l15;
        float bias = ib1[n];
#pragma unroll
        for (int i = 0; i < 4; ++i) {
            int row = row0 + q * 4 + i;
            t1[row * 256 + n] = fmaxf(acc[nt][i] + bias, 0.f);
        }
    }
}

// ---------------------------------------------------------------------------
// final+means (R6-verified "final v3"): t2 = relu(t1@iw2^T+ib2);
// integ = tanh(t2@iw3^T+ib3); heads; fused group-means (wave wv4 scans
// amat row b0+wv4, shuffle reduce). Deletes the means launch.
// ---------------------------------------------------------------------------
__global__ __launch_bounds__(256) void final_kernel(
    const float* __restrict__ t1, const unsigned short* __restrict__ amat,
    const float* __restrict__ iw2,
    const float* __restrict__ ib2, const float* __restrict__ iw3,
    const float* __restrict__ ib3,
    const float* __restrict__ hw_trend, const float* __restrict__ hb_trend,
    const float* __restrict__ hw_pat,   const float* __restrict__ hb_pat,
    const float* __restrict__ hw_key,   const float* __restrict__ hb_key,
    const float* __restrict__ hw_vol,   const float* __restrict__ hb_vol,
    const float* __restrict__ hw_conf,  const float* __restrict__ hb_conf,
    float* __restrict__ out)
{
    __shared__ float iw2s[64 * 257];
    __shared__ float iw3s[32 * 65];
    __shared__ float t1s[4][256];
    __shared__ float t2s[4][64];
    __shared__ float igs[4][32];
    __shared__ float mred[4][4];

    const int tid = threadIdx.x;
    const int b0  = blockIdx.x * 4;

    for (int i = tid; i < 16384; i += 256) {
        int u = i >> 8, k = i & 255;
        iw2s[u * 257 + k] = iw2[i];
    }
    for (int i = tid; i < 2048; i += 256) {
        int u = i >> 6, k = i & 63;
        iw3s[u * 65 + k] = iw3[i];
    }
    for (int i = tid; i < 1024; i += 256)
        t1s[i >> 8][i & 255] = t1[b0 * 256 + i];

    // ---- fused means: wave wv4 scans amat row b0+wv4 (316 short8 chunks)
    {
        const int lane = tid & 63, wv4 = tid >> 6;
        const unsigned short* arow = amat + (unsigned int)(b0 + wv4) * 2528;
        float parts[4] = {0.f, 0.f, 0.f, 0.f};
#pragma unroll
        for (int s = 0; s < 5; ++s) {
            int c = lane + 64 * s;
            if (c < 316) {
                short8 v = *(const short8*)(arow + c * 8);
#pragma unroll
                for (int e = 0; e < 8; ++e) {
                    int n = c * 8 + e;
                    float f = bf2f((unsigned short)v[e]);
                    if (n < 800)       parts[0] += f;
                    else if (n < 1500) parts[1] += f;
                    else if (n < 2100) parts[2] += f;
                    else               parts[3] += f;  // pad region adds 0
                }
            }
        }
#pragma unroll
        for (int g = 0; g < 4; ++g) {
            float v = parts[g];
            for (int s2 = 32; s2 > 0; s2 >>= 1) v += __shfl_down(v, s2, 64);
            if (lane == 0) mred[wv4][g] = v;
        }
    }
    __syncthreads();

    {
        const int r = tid >> 6, u = tid & 63;
        float acc = ib2[u];
        const float* wr = &iw2s[u * 257];
        const float* tr = &t1s[r][0];
#pragma unroll 4
        for (int k = 0; k < 256; ++k) acc = fmaf(tr[k], wr[k], acc);
        t2s[r][u] = fmaxf(acc, 0.f);
    }
    __syncthreads();

    if (tid < 128) {
        const int r = tid >> 5, u2 = tid & 31;
        float a2 = ib3[u2];
        const float* wr = &iw3s[u2 * 65];
        const float* tr = &t2s[r][0];
#pragma unroll 4
        for (int k = 0; k < 64; ++k) a2 = fmaf(tr[k], wr[k], a2);
        igs[r][u2] = tanhft(a2);
    }
    __syncthreads();

    if (tid < 60) {
        const int r = tid / 15, t15 = tid % 15;
        const int b = b0 + r;
        const float* w; const float* bb; int j, off;
        if (t15 < 3)        { w = hw_trend; bb = hb_trend; j = t15;     off = 0; }
        else if (t15 < 9)   { w = hw_pat;   bb = hb_pat;   j = t15 - 3; off = 3; }
        else if (t15 < 13)  { w = hw_key;   bb = hb_key;   j = t15 - 9; off = 9; }
        else if (t15 == 13) { w = hw_vol;   bb = hb_vol;   j = 0;       off = 13; }
        else                { w = hw_conf;  bb = hb_conf;  j = 0;       off = 14; }
        float a3 = bb[j];
#pragma unroll
        for (int k = 0; k < 32; ++k) a3 = fmaf(igs[r][k], w[j * 32 + k], a3);
        out[b * 20 + off + j] = a3;
        if (t15 == 14) out[b * 20 + 15] = sigf(a3);
    }
    if (tid < 16) {
        const int r = tid >> 2, g = tid & 3;
        const float inv[4] = {1.f / 800.f, 1.f / 700.f, 1.f / 600.f, 1.f / 400.f};
        out[(b0 + r) * 20 + 16 + g] = mred[r][g] * inv[g];
    }
}

// ---------------------------------------------------------------------------
extern "C" void kernel_launch(void* const* d_in, const int* in_sizes, int n_in,
                              void* d_out, int out_size, void* d_ws, size_t ws_size,
                              hipStream_t stream)
{
    const float* x        = (const float*)d_in[0];
    const int*   conn_idx = (const int*)  d_in[1];
    const float* w_ih0    = (const float*)d_in[2];
    const float* w_hh0    = (const float*)d_in[3];
    const float* b_ih0    = (const float*)d_in[4];
    const float* b_hh0    = (const float*)d_in[5];
    const float* w_ih1    = (const float*)d_in[6];
    const float* w_hh1    = (const float*)d_in[7];
    const float* b_ih1    = (const float*)d_in[8];
    const float* b_hh1    = (const float*)d_in[9];
    const float* pw1      = (const float*)d_in[10];
    const float* pb1      = (const float*)d_in[11];
    const float* pw2      = (const float*)d_in[12];
    const float* pb2      = (const float*)d_in[13];
    const float* conn_w   = (const float*)d_in[14];
    const float* sens     = (const float*)d_in[15];
    const float* thr      = (const float*)d_in[16];
    const float* iw1      = (const float*)d_in[17];
    const float* ib1      = (const float*)d_in[18];
    const float* iw2      = (const float*)d_in[19];
    const float* ib2      = (const float*)d_in[20];
    const float* iw3      = (const float*)d_in[21];
    const float* ib3      = (const float*)d_in[22];
    const float* hw_trend = (const float*)d_in[23];
    const float* hb_trend = (const float*)d_in[24];
    const float* hw_pat   = (const float*)d_in[25];
    const float* hb_pat   = (const float*)d_in[26];
    const float* hw_key   = (const float*)d_in[27];
    const float* hb_key   = (const float*)d_in[28];
    const float* hw_vol   = (const float*)d_in[29];
    const float* hb_vol   = (const float*)d_in[30];
    const float* hw_conf  = (const float*)d_in[31];
    const float* hb_conf  = (const float*)d_in[32];
    float* out = (float*)d_out;
    float* ws  = (float*)d_ws;

    // ws layout (float slots)
    unsigned short* whh0h = (unsigned short*)(ws);           // 32768 f
    unsigned short* wih1h = (unsigned short*)(ws + 32768);   // 32768 f
    unsigned short* whh1h = (unsigned short*)(ws + 65536);   // 32768 f
    float* bias0  = ws + 98304;   // 512
    float* bias1  = ws + 98816;   // 512
    float* h2     = ws + 99328;   // 131072
    float* base_  = ws + 230400;  // 32768
    float* weffT  = ws + 263168;  // 80000
    float* t1     = ws + 343168;  // 262144
    unsigned short* iw1b   = (unsigned short*)(ws + 605312); // 323584 f
    unsigned short* amatbf = (unsigned short*)(ws + 928896); // 1294336 f -> ends 2223232

    prep_all_kernel<<<2806, 256, 0, stream>>>(w_hh0, w_ih1, w_hh1,
                                              b_ih0, b_hh0, b_ih1, b_hh1,
                                              conn_idx, conn_w, iw1,
                                              whh0h, wih1h, whh1h, bias0, bias1,
                                              weffT, iw1b);
    lstm_kernel<<<256, 512, 0, stream>>>(x, whh0h, wih1h, whh1h, w_ih0,
                                         bias0, bias1, h2);
    phase2_kernel<<<256, 256, 0, stream>>>(h2, pw1, pb1, pw2, pb2, base_);
    za_kernel<<<640, 256, 0, stream>>>(base_, weffT, sens, thr, amatbf);
    gemm_iw1_kernel<<<dim3(8, 32), 128, 0, stream>>>(amatbf, iw1b, ib1, t1);
    final_kernel<<<256, 256, 0, stream>>>(t1, amatbf, iw2, ib2, iw3, ib3,
                                          hw_trend, hb_trend, hw_pat, hb_pat,
                                          hw_key, hb_key, hw_vol, hb_vol,
                                          hw_conf, hb_conf, out);
}